// Round 7
// baseline (879.460 us; speedup 1.0000x reference)
//
#include <hip/hip_runtime.h>

typedef _Float16 f16;
typedef _Float16 f16x2 __attribute__((ext_vector_type(2)));
typedef _Float16 f16x4 __attribute__((ext_vector_type(4)));
typedef _Float16 f16x8 __attribute__((ext_vector_type(8)));
typedef float f32x4 __attribute__((ext_vector_type(4)));

#define DEVI static __device__ __forceinline__

constexpr int S_  = 2048;
constexpr int H_  = 16;
constexpr int BH_ = 32;   // B*H

DEVI float softplus_(float x){ return logf(1.0f + expf(x)); }
DEVI float exp2_(float x){ return __builtin_amdgcn_exp2f(x); }

DEVI f16x2 cvt2(float a, float b){
  return __builtin_bit_cast(f16x2, __builtin_amdgcn_cvt_pkrtz(a, b));
}

DEVI f16x8 pack8(float4 a, float4 b){
  f16x2 p0 = cvt2(a.x, a.y);
  f16x2 p1 = cvt2(a.z, a.w);
  f16x2 p2 = cvt2(b.x, b.y);
  f16x2 p3 = cvt2(b.z, b.w);
  f16x8 o;
  o[0]=p0[0]; o[1]=p0[1]; o[2]=p1[0]; o[3]=p1[1];
  o[4]=p2[0]; o[5]=p2[1]; o[6]=p3[0]; o[7]=p3[1];
  return o;
}

DEVI void g2l16(const f16* g, f16* l){
  __builtin_amdgcn_global_load_lds(
      (const __attribute__((address_space(1))) void*)(g),
      (__attribute__((address_space(3))) void*)(l), 16, 0, 0);
}

// f32 -> f16 convert, 8 elems/thread
__global__ __launch_bounds__(256) void cvt_k(
    const float* __restrict__ src, f16* __restrict__ dst, int n8)
{
  int i = blockIdx.x*256 + threadIdx.x;
  if (i < n8){
    const float* s = src + (size_t)i*8;
    float4 a = *(const float4*)s, b = *(const float4*)(s+4);
    *(f16x8*)(dst + (size_t)i*8) = pack8(a,b);
  }
}

// ---------------------------------------------------------------------------
// f16 GEMM, m97-style, XCD-swizzled 1D grid.
// mode 0: grid 768 (32m x 24n), fused QKV
// mode 1: grid 256 (32m x 8n), out projection
// ---------------------------------------------------------------------------
__global__ __launch_bounds__(256) void gemm16_k(
    const f16* __restrict__ A, const f16* __restrict__ W,
    f16* __restrict__ q16, f16* __restrict__ k16, float* __restrict__ v32,
    float* __restrict__ o32f, int mode)
{
  constexpr int K = 1024;
  int id = blockIdx.x;
  int xcd = id & 7, w = id >> 3;
  int gm, gn;
  if (mode==0){ gm = (xcd&3)*8 + w/12; gn = (xcd>>2)*12 + w%12; }
  else        { gm = (xcd&3)*8 + w/4;  gn = (xcd>>2)*4  + (w&3); }
  int m0 = gm*128, n0 = gn*128;

  int tid = threadIdx.x, wave = tid>>6, lane = tid&63, lr_ = lane&15, lg = lane>>4;
  int wm = (wave&1)*64, wn = (wave>>1)*64;
  __shared__ __align__(16) f16 As[128*32];
  __shared__ __align__(16) f16 Ws[128*32];
  f32x4 acc[4][4];
  #pragma unroll
  for (int a=0;a<4;a++)
    #pragma unroll
    for (int b=0;b<4;b++) acc[a][b] = (f32x4){0.f,0.f,0.f,0.f};

  int r1 = tid>>2,        o1 = (tid&3)*8;
  int r2 = (tid+256)>>2,  o2 = ((tid+256)&3)*8;
  const f16* a1 = A + (size_t)(m0+r1)*K + o1;
  const f16* a2 = A + (size_t)(m0+r2)*K + o2;
  const f16* w1 = W + (size_t)(n0+r1)*K + o1;
  const f16* w2 = W + (size_t)(n0+r2)*K + o2;
  f16* la1 = &As[tid*8];  f16* la2 = &As[(tid+256)*8];
  f16* lw1 = &Ws[tid*8];  f16* lw2 = &Ws[(tid+256)*8];

  for (int kt=0; kt<K; kt+=32){
    g2l16(a1 + kt, la1);
    g2l16(a2 + kt, la2);
    g2l16(w1 + kt, lw1);
    g2l16(w2 + kt, lw2);
    __syncthreads();
    f16x8 af[4], bf[4];
    #pragma unroll
    for (int mf=0;mf<4;mf++) af[mf] = *(const f16x8*)&As[(wm+mf*16+lr_)*32 + lg*8];
    #pragma unroll
    for (int nf=0;nf<4;nf++) bf[nf] = *(const f16x8*)&Ws[(wn+nf*16+lr_)*32 + lg*8];
    #pragma unroll
    for (int mf=0;mf<4;mf++)
      #pragma unroll
      for (int nf=0;nf<4;nf++)
        acc[mf][nf] = __builtin_amdgcn_mfma_f32_16x16x32_f16(af[mf], bf[nf], acc[mf][nf], 0,0,0);
    __syncthreads();
  }
  #pragma unroll
  for (int mf=0;mf<4;mf++)
    #pragma unroll
    for (int nf=0;nf<4;nf++)
      #pragma unroll
      for (int rg=0;rg<4;rg++){
        int grow = m0+wm+mf*16+lg*4+rg;
        int gcol = n0+wn+nf*16+lr_;
        float vv = acc[mf][nf][rg];
        if (mode==0){
          int mat = gcol>>10, col = gcol&1023;
          int b = grow>>11, s = grow&2047, hh = col>>6, d2 = col&63;
          size_t gi = (((size_t)(b*16+hh))*S_ + s)*64 + d2;
          if (mat==0)      q16[gi] = (f16)vv;
          else if (mat==1) k16[gi] = (f16)vv;
          else             v32[gi] = vv;
        } else {
          o32f[(size_t)grow*1024 + gcol] = vv;
        }
      }
}

// ---------------------------------------------------------------------------
__global__ __launch_bounds__(256) void stats_k(
    const f16* __restrict__ q16, const f16* __restrict__ k16,
    const float* __restrict__ bwp, const float* __restrict__ dsp, const float* __restrict__ rgp,
    float* __restrict__ bs, float* __restrict__ ct, float* __restrict__ dp)
{
  int g = blockIdx.x*256 + threadIdx.x;
  int h = (g>>11)&15;
  float bw = softplus_(bwp[0]) + 1e-6f;
  float c2 = 1.f/(2.f*bw*bw*0.6931471805599453f);
  const f16* qr = q16 + (size_t)g*64;
  const f16* kr = k16 + (size_t)g*64;
  float qsq=0.f, ksq=0.f, qk=0.f;
  #pragma unroll
  for (int c=0;c<8;c++){
    f16x8 qv = *(const f16x8*)(qr + c*8);
    f16x8 kv = *(const f16x8*)(kr + c*8);
    #pragma unroll
    for (int j=0;j<8;j++){
      float a = (float)qv[j], b = (float)kv[j];
      qsq += a*a; ksq += b*b; qk += a*b;
    }
  }
  bs[g] = -qsq*c2;
  ct[g] = -ksq*c2;
  float dist = fmaxf(qsq + ksq - 2.f*qk, 0.f);
  float kd = exp2_(-dist*c2);
  dp[g] = softplus_(kd)*dsp[h] + rgp[0];
}

// lr[h,s,p] = sum_r pos[s,r]*hp[h,r,p]
__global__ __launch_bounds__(256) void lr_k(
    const float* __restrict__ pos, const float* __restrict__ hpj, float* __restrict__ lr32)
{
  int g = blockIdx.x*256 + threadIdx.x;
  int p = g&15, s = (g>>4)&2047, h = g>>15;
  float acc = 0.f;
  #pragma unroll
  for (int r=0;r<16;r++) acc += pos[s*16+r]*hpj[(h*16+r)*16+p];
  lr32[g] = acc;
}

// ---------------------------------------------------------------------------
// Fused apply v5: R = K @ alpha, 512 thr (8 waves x 32 s-rows), dbuf LDS,
// pad 68 (bank-uniform), fused lr^T@resid partial per wave -> rbuf (64 chunks).
// mode 0: resid = v - R - lam*alpha, rbuf partials    mode 1: y16 = R
// ---------------------------------------------------------------------------
__global__ __launch_bounds__(512,1) void apply_k(
    const f16* __restrict__ q16, const f16* __restrict__ k16,
    const f16* __restrict__ alphaT,
    const float* __restrict__ bs, const float* __restrict__ ct,
    const float* __restrict__ v32, const float* __restrict__ alpha32,
    const float* __restrict__ bwp, const float* __restrict__ lmp,
    const float* __restrict__ lr32, float* __restrict__ rbuf,
    float* __restrict__ resid, f16* __restrict__ y16,
    int mode)
{
  int id = blockIdx.x;
  int bh = ((id&7)<<2) | ((id>>3)&3);
  int s0 = (id>>5)*256;

  float bw = softplus_(bwp[0]) + 1e-6f;
  float c2 = 1.f/(2.f*bw*bw*0.6931471805599453f);
  float acoef = 2.f*c2;

  int tid = threadIdx.x, wave = tid>>6, lane = tid&63, lr_ = lane&15, lg = lane>>4;
  int sw = s0 + wave*32;

  f16x8 q0[2], q1[2]; float bsv[2];
  #pragma unroll
  for (int sub=0; sub<2; sub++){
    const f16* qr = q16 + ((size_t)bh*S_ + sw + sub*16 + lr_)*64;
    q0[sub] = *(const f16x8*)(qr + lg*8);
    q1[sub] = *(const f16x8*)(qr + 32 + lg*8);
    bsv[sub] = bs[bh*S_ + sw + sub*16 + lr_];
  }

  __shared__ __align__(16) f16 ks[2][64][68];   // stride 68: bank-uniform
  __shared__ __align__(16) f16 at[2][64][68];
  __shared__ __align__(16) float cts[2][64];

  f32x4 racc[2][4];
  #pragma unroll
  for (int sub=0;sub<2;sub++)
    #pragma unroll
    for (int df=0;df<4;df++) racc[sub][df] = (f32x4){0.f,0.f,0.f,0.f};

  int srow = tid>>3, scol = (tid&7)*8;
  const f16* kg = k16    + ((size_t)bh*S_ + srow)*64 + scol;
  const f16* ag = alphaT + ((size_t)bh*64 + srow)*S_ + scol;
  const float* ctb = ct + (size_t)bh*S_;
  int lct = tid&63;

  f16x8 kv, av; float ctp;
  auto LOADT = [&](int t0){
    kv  = *(const f16x8*)(kg + (size_t)t0*64);
    av  = *(const f16x8*)(ag + t0);
    ctp = ctb[t0 + lct];
  };
  auto STORET = [&](int b){
    *(f16x8*)&ks[b][srow][scol] = kv;
    *(f16x8*)&at[b][srow][scol] = av;
    cts[b][lct] = ctp;
  };

  LOADT(0);
  STORET(0);
  LOADT(64);
  __syncthreads();

  for (int t0=0; t0<S_; t0+=64){
    int b = (t0>>6)&1;
    if (t0+64 < S_)  STORET(b^1);
    if (t0+128 < S_) LOADT(t0+128);
    #pragma unroll
    for (int tf=0; tf<4; tf++){
      f16x8 ka0 = *(const f16x8*)&ks[b][tf*16+lr_][lg*8];
      f16x8 ka1 = *(const f16x8*)&ks[b][tf*16+lr_][32+lg*8];
      f32x4 sacc[2];
      #pragma unroll
      for (int sub=0; sub<2; sub++){
        sacc[sub] = (f32x4){0.f,0.f,0.f,0.f};
        sacc[sub] = __builtin_amdgcn_mfma_f32_16x16x32_f16(ka0, q0[sub], sacc[sub], 0,0,0);
        sacc[sub] = __builtin_amdgcn_mfma_f32_16x16x32_f16(ka1, q1[sub], sacc[sub], 0,0,0);
      }
      f32x4 ctv = *(const f32x4*)&cts[b][tf*16 + lg*4];
      f16x4 paf[2];
      #pragma unroll
      for (int sub=0; sub<2; sub++){
        float p0 = exp2_(fminf(fmaf(acoef, sacc[sub][0], bsv[sub] + ctv[0]), 0.f));
        float p1 = exp2_(fminf(fmaf(acoef, sacc[sub][1], bsv[sub] + ctv[1]), 0.f));
        float p2 = exp2_(fminf(fmaf(acoef, sacc[sub][2], bsv[sub] + ctv[2]), 0.f));
        float p3 = exp2_(fminf(fmaf(acoef, sacc[sub][3], bsv[sub] + ctv[3]), 0.f));
        f16x2 lo = cvt2(p0,p1), hi = cvt2(p2,p3);
        paf[sub][0]=lo[0]; paf[sub][1]=lo[1]; paf[sub][2]=hi[0]; paf[sub][3]=hi[1];
      }
      #pragma unroll
      for (int df=0; df<4; df++){
        f16x4 bfr = *(const f16x4*)&at[b][df*16+lr_][tf*16+lg*4];
        #pragma unroll
        for (int sub=0; sub<2; sub++)
          racc[sub][df] = __builtin_amdgcn_mfma_f32_16x16x16f16(paf[sub], bfr, racc[sub][df], 0,0,0);
      }
    }
    __syncthreads();
  }

  if (mode==0){
    float lam = softplus_(lmp[0]) + 1e-6f;
    int h = bh&15;
    float partial[16][4];
    #pragma unroll
    for (int r=0;r<16;r++)
      #pragma unroll
      for (int df=0;df<4;df++) partial[r][df] = 0.f;

    #pragma unroll
    for (int sub=0; sub<2; sub++)
      #pragma unroll
      for (int rg=0; rg<4; rg++){
        int s = sw + sub*16 + lg*4 + rg;
        const float* lrow = lr32 + ((size_t)h*S_ + s)*16;
        f32x4 l0 = *(const f32x4*)lrow;
        f32x4 l1 = *(const f32x4*)(lrow+4);
        f32x4 l2 = *(const f32x4*)(lrow+8);
        f32x4 l3 = *(const f32x4*)(lrow+12);
        float lv[16] = {l0[0],l0[1],l0[2],l0[3], l1[0],l1[1],l1[2],l1[3],
                        l2[0],l2[1],l2[2],l2[3], l3[0],l3[1],l3[2],l3[3]};
        #pragma unroll
        for (int df=0; df<4; df++){
          int dd = df*16 + lr_;
          size_t gi = ((size_t)bh*S_ + s)*64 + dd;
          float rv = v32[gi] - racc[sub][df][rg] - lam*alpha32[gi];
          resid[gi] = rv;
          #pragma unroll
          for (int r=0; r<16; r++) partial[r][df] = fmaf(lv[r], rv, partial[r][df]);
        }
      }

    // reduce across lane-groups (lanes ^16, ^32), then lane<16 writes
    int chunk = (id>>5)*8 + wave;          // 0..63
    #pragma unroll
    for (int r=0;r<16;r++)
      #pragma unroll
      for (int df=0;df<4;df++){
        float v = partial[r][df];
        v += __shfl_xor(v, 16);
        v += __shfl_xor(v, 32);
        if (lane < 16)
          rbuf[((size_t)((chunk*32+bh)*16 + r))*64 + df*16 + lane] = v;
      }
  } else {
    int b2 = bh>>4, h = bh&15;
    #pragma unroll
    for (int sub=0; sub<2; sub++)
      #pragma unroll
      for (int df=0; df<4; df++)
        #pragma unroll
        for (int rg=0; rg<4; rg++){
          int dd = df*16 + lr_;
          int s = sw + sub*16 + lg*4 + rg;
          y16[((size_t)(b2*S_+s))*1024 + h*64 + dd] = (f16)racc[sub][df][rg];
        }
  }
}

// rbuf[sc,bh,r,d] = sum_{s in chunk sc} lr[h,s,r]*v[bh,s,d]  (8 chunks of 256)
// used only for iteration 1 (resid = v)
__global__ __launch_bounds__(256) void reduce_t_k(
    const float* __restrict__ lr32, const float* __restrict__ rsd, float* __restrict__ rbuf)
{
  int dblk = blockIdx.x, bh = blockIdx.y, sc = blockIdx.z, h = bh&15;
  int tid = threadIdx.x, r = tid>>4, dc = tid&15;
  __shared__ __align__(16) float lr_s[128][20];
  __shared__ __align__(16) float rs[128][20];
  float acc = 0.f;
  int row = tid>>1, c8 = (tid&1)*8;
  for (int s0=sc*256; s0<sc*256+256; s0+=128){
    const float* lp = lr32 + ((size_t)h*S_ + s0 + row)*16 + c8;
    const float* rp = rsd  + ((size_t)bh*S_ + s0 + row)*64 + dblk*16 + c8;
    float4 l0 = *(const float4*)lp, l1 = *(const float4*)(lp+4);
    float4 r0 = *(const float4*)rp, r1 = *(const float4*)(rp+4);
    *(float4*)&lr_s[row][c8]   = l0; *(float4*)&lr_s[row][c8+4] = l1;
    *(float4*)&rs[row][c8]     = r0; *(float4*)&rs[row][c8+4]   = r1;
    __syncthreads();
    #pragma unroll 8
    for (int ss=0; ss<128; ss++) acc += lr_s[ss][r]*rs[ss][dc];
    __syncthreads();
  }
  rbuf[((size_t)(sc*32+bh)*16 + r)*64 + dblk*16 + dc] = acc;
}

// alpha = clip(alpha + dp*resid + lr@t), t = sum of nchunk rbuf partials
__global__ __launch_bounds__(256) void update_k(
    const float* __restrict__ rsd, const float* __restrict__ alpha_in, int alpha_zero,
    const float* __restrict__ lr32, const float* __restrict__ rbuf, int nchunk,
    const float* __restrict__ dpp,
    float* __restrict__ alpha_out, f16* __restrict__ alphaT)
{
  int sblk = blockIdx.x, bh = blockIdx.y, h = bh&15, s0 = sblk*64;
  int tid = threadIdx.x;
  __shared__ __align__(16) float tb_s[16][64];
  __shared__ __align__(16) float lr_s[64][20];
  __shared__ float dp_s[64];
  __shared__ __align__(16) f16 at_s[64][72];
  {
    float4 t4 = {0.f,0.f,0.f,0.f};
    for (int sc=0; sc<nchunk; sc++){
      float4 p4 = *(const float4*)(rbuf + (size_t)(sc*32+bh)*1024 + tid*4);
      t4.x += p4.x; t4.y += p4.y; t4.z += p4.z; t4.w += p4.w;
    }
    *(float4*)&((float*)tb_s)[tid*4] = t4;
    int row = tid>>2, c4 = (tid&3)*4;
    float4 l4 = *(const float4*)(lr32 + ((size_t)h*S_ + s0 + row)*16 + c4);
    *(float4*)&lr_s[row][c4] = l4;
    if (tid < 64) dp_s[tid] = dpp[(size_t)bh*S_ + s0 + tid];
  }
  __syncthreads();
  #pragma unroll
  for (int i=0;i<16;i++){
    int idx = i*256 + tid;
    int sl = idx>>6, dd = idx&63;
    size_t gi = ((size_t)bh*S_ + s0 + sl)*64 + dd;
    float rv = rsd[gi];
    float av = alpha_zero ? 0.f : alpha_in[gi];
    float acc = av + dp_s[sl]*rv;
    #pragma unroll
    for (int rr=0; rr<16; rr++) acc += lr_s[sl][rr]*tb_s[rr][dd];
    acc = fminf(fmaxf(acc, -10.f), 10.f);
    alpha_out[gi] = acc;
    at_s[dd][sl] = (f16)acc;
  }
  __syncthreads();
  int dd = tid>>2, c16 = (tid&3)*16;
  f16* dst = alphaT + ((size_t)bh*64 + dd)*S_ + s0 + c16;
  *(f16x8*)dst     = *(const f16x8*)&at_s[dd][c16];
  *(f16x8*)(dst+8) = *(const f16x8*)&at_s[dd][c16+8];
}

// ---------------------------------------------------------------------------
extern "C" void kernel_launch(void* const* d_in, const int* in_sizes, int n_in,
                              void* d_out, int out_size, void* d_ws, size_t ws_size,
                              hipStream_t stream)
{
  const float* x   = (const float*)d_in[0];
  const float* wq  = (const float*)d_in[1];
  const float* wk  = (const float*)d_in[2];
  const float* wv  = (const float*)d_in[3];
  const float* wo  = (const float*)d_in[4];
  const float* bwp = (const float*)d_in[5];
  const float* dsp = (const float*)d_in[6];
  const float* rgp = (const float*)d_in[7];
  const float* pos = (const float*)d_in[8];
  const float* hpj = (const float*)d_in[9];
  const float* lmp = (const float*)d_in[10];
  float* outp = (float*)d_out;

  char* base = (char*)d_ws;
  size_t off = 0;
  auto carve = [&](size_t bytes)->char* {
    char* p = base + off; off += (bytes + 255) & ~(size_t)255; return p;
  };
  f16*   x16    = (f16*)  carve((size_t)4096*1024*2);     // 8 MB
  f16*   wqkv16 = (f16*)  carve((size_t)3072*1024*2);     // 6 MB
  f16*   wo16   = (f16*)  carve((size_t)1024*1024*2);     // 2 MB
  f16*   q16    = (f16*)  carve((size_t)BH_*S_*64*2);     // 8 MB
  f16*   k16    = (f16*)  carve((size_t)BH_*S_*64*2);     // 8 MB
  float* v32    = (float*)carve((size_t)BH_*S_*64*4);     // 16 MB
  float* alpha  = (float*)carve((size_t)BH_*S_*64*4);     // 16 MB
  f16*   alphaT = (f16*)  carve((size_t)BH_*64*S_*2);     // 8 MB
  float* resid  = (float*)carve((size_t)BH_*S_*64*4);     // 16 MB
  f16*   y16    = (f16*)  carve((size_t)4096*1024*2);     // 8 MB
  float* bs     = (float*)carve((size_t)BH_*S_*4);
  float* ct     = (float*)carve((size_t)BH_*S_*4);
  float* dp     = (float*)carve((size_t)BH_*S_*4);
  float* lr32   = (float*)carve((size_t)H_*S_*16*4);      // 2 MB
  float* rbuf   = (float*)carve((size_t)64*BH_*16*64*4);  // 8 MB

  // f32 -> f16 conversions
  cvt_k<<<2048,256,0,stream>>>(x,  x16,               4096*1024/8);
  cvt_k<<< 512,256,0,stream>>>(wq, wqkv16,            1024*1024/8);
  cvt_k<<< 512,256,0,stream>>>(wk, wqkv16+1024*1024,  1024*1024/8);
  cvt_k<<< 512,256,0,stream>>>(wv, wqkv16+2*1024*1024,1024*1024/8);
  cvt_k<<< 512,256,0,stream>>>(wo, wo16,              1024*1024/8);
  // fused QKV projection
  gemm16_k<<<768,256,0,stream>>>(x16, wqkv16, q16, k16, v32, nullptr, 0);
  stats_k<<<256,256,0,stream>>>(q16,k16,bwp,dsp,rgp,bs,ct,dp);
  lr_k<<<2048,256,0,stream>>>(pos,hpj,lr32);
  // iteration 1: alpha=0 -> residual = v
  reduce_t_k<<<dim3(4,32,8),256,0,stream>>>(lr32, v32, rbuf);
  update_k<<<dim3(32,32),256,0,stream>>>(v32, alpha, 1, lr32, rbuf, 8, dp, alpha, alphaT);
  // iterations 2..8 (apply fuses resid + lr^T@resid partials)
  for (int it=1; it<8; ++it){
    apply_k<<<256,512,0,stream>>>(q16,k16,alphaT,bs,ct,v32,alpha,bwp,lmp,lr32,rbuf,resid,nullptr,0);
    update_k<<<dim3(32,32),256,0,stream>>>(resid, alpha, 0, lr32, rbuf, 64, dp, alpha, alphaT);
  }
  // final: out = K @ alpha, then output projection
  apply_k<<<256,512,0,stream>>>(q16,k16,alphaT,bs,ct,v32,alpha,bwp,lmp,lr32,rbuf,resid,y16,1);
  gemm16_k<<<256,256,0,stream>>>(y16, wo16, nullptr, nullptr, nullptr, outp, 1);
}

// Round 9
// 849.931 us; speedup vs baseline: 1.0347x; 1.0347x over previous
//
#include <hip/hip_runtime.h>

typedef _Float16 f16;
typedef _Float16 f16x2 __attribute__((ext_vector_type(2)));
typedef _Float16 f16x4 __attribute__((ext_vector_type(4)));
typedef _Float16 f16x8 __attribute__((ext_vector_type(8)));
typedef float f32x4 __attribute__((ext_vector_type(4)));

#define DEVI static __device__ __forceinline__

constexpr int S_  = 2048;
constexpr int H_  = 16;
constexpr int BH_ = 32;   // B*H

DEVI float softplus_(float x){ return logf(1.0f + expf(x)); }
DEVI float exp2_(float x){ return __builtin_amdgcn_exp2f(x); }

DEVI f16x2 cvt2(float a, float b){
  return __builtin_bit_cast(f16x2, __builtin_amdgcn_cvt_pkrtz(a, b));
}

DEVI f16x8 pack8(float4 a, float4 b){
  f16x2 p0 = cvt2(a.x, a.y);
  f16x2 p1 = cvt2(a.z, a.w);
  f16x2 p2 = cvt2(b.x, b.y);
  f16x2 p3 = cvt2(b.z, b.w);
  f16x8 o;
  o[0]=p0[0]; o[1]=p0[1]; o[2]=p1[0]; o[3]=p1[1];
  o[4]=p2[0]; o[5]=p2[1]; o[6]=p3[0]; o[7]=p3[1];
  return o;
}

DEVI void g2l16(const f16* g, f16* l){
  __builtin_amdgcn_global_load_lds(
      (const __attribute__((address_space(1))) void*)(g),
      (__attribute__((address_space(3))) void*)(l), 16, 0, 0);
}

// f32 -> f16 convert, 8 elems/thread
__global__ __launch_bounds__(256) void cvt_k(
    const float* __restrict__ src, f16* __restrict__ dst, int n8)
{
  int i = blockIdx.x*256 + threadIdx.x;
  if (i < n8){
    const float* s = src + (size_t)i*8;
    float4 a = *(const float4*)s, b = *(const float4*)(s+4);
    *(f16x8*)(dst + (size_t)i*8) = pack8(a,b);
  }
}

// ---------------------------------------------------------------------------
// f16 GEMM, BK=64, XCD-swizzled 1D grid.
// mode 0: grid 768 (32m x 24n), fused QKV   mode 1: grid 256 (32m x 8n)
// ---------------------------------------------------------------------------
__global__ __launch_bounds__(256) void gemm16_k(
    const f16* __restrict__ A, const f16* __restrict__ W,
    f16* __restrict__ q16, f16* __restrict__ k16, float* __restrict__ v32,
    float* __restrict__ o32f, int mode)
{
  constexpr int K = 1024;
  int id = blockIdx.x;
  int xcd = id & 7, w = id >> 3;
  int gm, gn;
  if (mode==0){ gm = (xcd&3)*8 + w/12; gn = (xcd>>2)*12 + w%12; }
  else        { gm = (xcd&3)*8 + w/4;  gn = (xcd>>2)*4  + (w&3); }
  int m0 = gm*128, n0 = gn*128;

  int tid = threadIdx.x, wave = tid>>6, lane = tid&63, lr_ = lane&15, lg = lane>>4;
  int wm = (wave&1)*64, wn = (wave>>1)*64;
  __shared__ __align__(16) f16 As[128*64];
  __shared__ __align__(16) f16 Ws[128*64];
  f32x4 acc[4][4];
  #pragma unroll
  for (int a=0;a<4;a++)
    #pragma unroll
    for (int b=0;b<4;b++) acc[a][b] = (f32x4){0.f,0.f,0.f,0.f};

  // staging: 1024 16B-chunks per matrix per K-step; thread owns 4 of each
  const f16 *ap[4], *wp[4]; f16 *la[4], *lw[4];
  #pragma unroll
  for (int c=0;c<4;c++){
    int q = tid + c*256;
    int r = q>>3, o = (q&7)*8;
    ap[c] = A + (size_t)(m0+r)*K + o;
    wp[c] = W + (size_t)(n0+r)*K + o;
    la[c] = &As[q*8];
    lw[c] = &Ws[q*8];
  }

  for (int kt=0; kt<K; kt+=64){
    #pragma unroll
    for (int c=0;c<4;c++){ g2l16(ap[c]+kt, la[c]); g2l16(wp[c]+kt, lw[c]); }
    __syncthreads();
    #pragma unroll
    for (int ks=0; ks<2; ks++){
      f16x8 af[4], bf[4];
      #pragma unroll
      for (int mf=0;mf<4;mf++) af[mf] = *(const f16x8*)&As[(wm+mf*16+lr_)*64 + ks*32 + lg*8];
      #pragma unroll
      for (int nf=0;nf<4;nf++) bf[nf] = *(const f16x8*)&Ws[(wn+nf*16+lr_)*64 + ks*32 + lg*8];
      #pragma unroll
      for (int mf=0;mf<4;mf++)
        #pragma unroll
        for (int nf=0;nf<4;nf++)
          acc[mf][nf] = __builtin_amdgcn_mfma_f32_16x16x32_f16(af[mf], bf[nf], acc[mf][nf], 0,0,0);
    }
    __syncthreads();
  }
  #pragma unroll
  for (int mf=0;mf<4;mf++)
    #pragma unroll
    for (int nf=0;nf<4;nf++)
      #pragma unroll
      for (int rg=0;rg<4;rg++){
        int grow = m0+wm+mf*16+lg*4+rg;
        int gcol = n0+wn+nf*16+lr_;
        float vv = acc[mf][nf][rg];
        if (mode==0){
          int mat = gcol>>10, col = gcol&1023;
          int b = grow>>11, s = grow&2047, hh = col>>6, d2 = col&63;
          size_t gi = (((size_t)(b*16+hh))*S_ + s)*64 + d2;
          if (mat==0)      q16[gi] = (f16)vv;
          else if (mat==1) k16[gi] = (f16)vv;
          else             v32[gi] = vv;
        } else {
          o32f[(size_t)grow*1024 + gcol] = vv;
        }
      }
}

// ---------------------------------------------------------------------------
__global__ __launch_bounds__(256) void stats_k(
    const f16* __restrict__ q16, const f16* __restrict__ k16,
    const float* __restrict__ bwp, const float* __restrict__ dsp, const float* __restrict__ rgp,
    float* __restrict__ bs, float* __restrict__ ct, float* __restrict__ dp)
{
  int g = blockIdx.x*256 + threadIdx.x;
  int h = (g>>11)&15;
  float bw = softplus_(bwp[0]) + 1e-6f;
  float c2 = 1.f/(2.f*bw*bw*0.6931471805599453f);
  const f16* qr = q16 + (size_t)g*64;
  const f16* kr = k16 + (size_t)g*64;
  float qsq=0.f, ksq=0.f, qk=0.f;
  #pragma unroll
  for (int c=0;c<8;c++){
    f16x8 qv = *(const f16x8*)(qr + c*8);
    f16x8 kv = *(const f16x8*)(kr + c*8);
    #pragma unroll
    for (int j=0;j<8;j++){
      float a = (float)qv[j], b = (float)kv[j];
      qsq += a*a; ksq += b*b; qk += a*b;
    }
  }
  bs[g] = -qsq*c2;
  ct[g] = -ksq*c2;
  float dist = fmaxf(qsq + ksq - 2.f*qk, 0.f);
  float kd = exp2_(-dist*c2);
  dp[g] = softplus_(kd)*dsp[h] + rgp[0];
}

// lr[h,s,p] = sum_r pos[s,r]*hp[h,r,p]
__global__ __launch_bounds__(256) void lr_k(
    const float* __restrict__ pos, const float* __restrict__ hpj, float* __restrict__ lr32)
{
  int g = blockIdx.x*256 + threadIdx.x;
  int p = g&15, s = (g>>4)&2047, h = g>>15;
  float acc = 0.f;
  #pragma unroll
  for (int r=0;r<16;r++) acc += pos[s*16+r]*hpj[(h*16+r)*16+p];
  lr32[g] = acc;
}

// ---------------------------------------------------------------------------
// Fused apply v6: Rpart = K[:, thalf] @ alpha[thalf]. 512 thr (8 waves x 32 s),
// t-split x2 -> grid 512 (2 blocks/CU, 4 waves/SIMD), dbuf LDS, pad 68.
// ---------------------------------------------------------------------------
__global__ __launch_bounds__(512,4) void apply_k(
    const f16* __restrict__ q16, const f16* __restrict__ k16,
    const f16* __restrict__ alphaT,
    const float* __restrict__ bs, const float* __restrict__ ct,
    const float* __restrict__ bwp,
    float* __restrict__ Rp)
{
  int id = blockIdx.x;
  int bh = ((id&7)<<2) | ((id>>3)&3);
  int s0 = ((id>>5)&7)*256;
  int thalf = id>>8;
  int tb = thalf*1024;

  float bw = softplus_(bwp[0]) + 1e-6f;
  float c2 = 1.f/(2.f*bw*bw*0.6931471805599453f);
  float acoef = 2.f*c2;

  int tid = threadIdx.x, wave = tid>>6, lane = tid&63, lr_ = lane&15, lg = lane>>4;
  int sw = s0 + wave*32;

  f16x8 q0[2], q1[2]; float bsv[2];
  #pragma unroll
  for (int sub=0; sub<2; sub++){
    const f16* qr = q16 + ((size_t)bh*S_ + sw + sub*16 + lr_)*64;
    q0[sub] = *(const f16x8*)(qr + lg*8);
    q1[sub] = *(const f16x8*)(qr + 32 + lg*8);
    bsv[sub] = bs[bh*S_ + sw + sub*16 + lr_];
  }

  __shared__ __align__(16) f16 ks[2][64][68];   // stride 68: bank-uniform
  __shared__ __align__(16) f16 at[2][64][68];
  __shared__ __align__(16) float cts[2][64];

  f32x4 racc[2][4];
  #pragma unroll
  for (int sub=0;sub<2;sub++)
    #pragma unroll
    for (int df=0;df<4;df++) racc[sub][df] = (f32x4){0.f,0.f,0.f,0.f};

  int srow = tid>>3, scol = (tid&7)*8;
  const f16* kg = k16    + ((size_t)bh*S_ + srow)*64 + scol;
  const f16* ag = alphaT + ((size_t)bh*64 + srow)*S_ + scol;
  const float* ctb = ct + (size_t)bh*S_;
  int lct = tid&63;

  f16x8 kv, av; float ctp;
  auto LOADT = [&](int t0){
    kv  = *(const f16x8*)(kg + (size_t)t0*64);
    av  = *(const f16x8*)(ag + t0);
    ctp = ctb[t0 + lct];
  };
  auto STORET = [&](int b){
    *(f16x8*)&ks[b][srow][scol] = kv;
    *(f16x8*)&at[b][srow][scol] = av;
    cts[b][lct] = ctp;
  };

  int tend = tb + 1024;
  LOADT(tb);
  STORET(0);
  LOADT(tb+64);
  __syncthreads();

  for (int t0=tb; t0<tend; t0+=64){
    int b = ((t0-tb)>>6)&1;
    if (t0+64 < tend)  STORET(b^1);
    if (t0+128 < tend) LOADT(t0+128);
    #pragma unroll
    for (int tf=0; tf<4; tf++){
      f16x8 ka0 = *(const f16x8*)&ks[b][tf*16+lr_][lg*8];
      f16x8 ka1 = *(const f16x8*)&ks[b][tf*16+lr_][32+lg*8];
      f32x4 sacc[2];
      #pragma unroll
      for (int sub=0; sub<2; sub++){
        sacc[sub] = (f32x4){0.f,0.f,0.f,0.f};
        sacc[sub] = __builtin_amdgcn_mfma_f32_16x16x32_f16(ka0, q0[sub], sacc[sub], 0,0,0);
        sacc[sub] = __builtin_amdgcn_mfma_f32_16x16x32_f16(ka1, q1[sub], sacc[sub], 0,0,0);
      }
      f32x4 ctv = *(const f32x4*)&cts[b][tf*16 + lg*4];
      f16x4 paf[2];
      #pragma unroll
      for (int sub=0; sub<2; sub++){
        float p0 = exp2_(fminf(fmaf(acoef, sacc[sub][0], bsv[sub] + ctv[0]), 0.f));
        float p1 = exp2_(fminf(fmaf(acoef, sacc[sub][1], bsv[sub] + ctv[1]), 0.f));
        float p2 = exp2_(fminf(fmaf(acoef, sacc[sub][2], bsv[sub] + ctv[2]), 0.f));
        float p3 = exp2_(fminf(fmaf(acoef, sacc[sub][3], bsv[sub] + ctv[3]), 0.f));
        f16x2 lo = cvt2(p0,p1), hi = cvt2(p2,p3);
        paf[sub][0]=lo[0]; paf[sub][1]=lo[1]; paf[sub][2]=hi[0]; paf[sub][3]=hi[1];
      }
      #pragma unroll
      for (int df=0; df<4; df++){
        f16x4 bfr = *(const f16x4*)&at[b][df*16+lr_][tf*16+lg*4];
        #pragma unroll
        for (int sub=0; sub<2; sub++)
          racc[sub][df] = __builtin_amdgcn_mfma_f32_16x16x16f16(paf[sub], bfr, racc[sub][df], 0,0,0);
      }
    }
    __syncthreads();
  }

  float* rp = Rp + (size_t)thalf*BH_*S_*64;
  #pragma unroll
  for (int sub=0; sub<2; sub++)
    #pragma unroll
    for (int df=0; df<4; df++)
      #pragma unroll
      for (int rg=0; rg<4; rg++){
        int dd = df*16 + lr_;
        int s = sw + sub*16 + lg*4 + rg;
        rp[((size_t)bh*S_ + s)*64 + dd] = racc[sub][df][rg];
      }
}

// combine partial R halves into f16 y (attn-output layout)
__global__ __launch_bounds__(256) void combine_y_k(
    const float* __restrict__ Rp, f16* __restrict__ y16)
{
  int i = blockIdx.x*256 + threadIdx.x;      // 8 elems each, 4.19M total
  size_t g8 = (size_t)i*8;
  int dd = (int)(g8 & 63), s = (int)((g8>>6) & 2047), bh = (int)(g8>>17);
  const float* r0 = Rp + g8;
  const float* r1 = Rp + (size_t)BH_*S_*64 + g8;
  float4 a0 = *(const float4*)r0, a1 = *(const float4*)(r0+4);
  float4 b0 = *(const float4*)r1, b1 = *(const float4*)(r1+4);
  a0.x+=b0.x; a0.y+=b0.y; a0.z+=b0.z; a0.w+=b0.w;
  a1.x+=b1.x; a1.y+=b1.y; a1.z+=b1.z; a1.w+=b1.w;
  int b = bh>>4, h = bh&15;
  *(f16x8*)(y16 + ((size_t)(b*S_+s))*1024 + h*64 + dd) = pack8(a0,a1);
}

// partials from v (iteration 1): rbuf[sc,bh,r,d] = sum_s lr*v
__global__ __launch_bounds__(256) void reduce_t_k(
    const float* __restrict__ lr32, const float* __restrict__ rsd, float* __restrict__ rbuf)
{
  int dblk = blockIdx.x, bh = blockIdx.y, sc = blockIdx.z, h = bh&15;
  int tid = threadIdx.x, r = tid>>4, dc = tid&15;
  __shared__ __align__(16) float lr_s[128][20];
  __shared__ __align__(16) float rs[128][20];
  float acc = 0.f;
  int row = tid>>1, c8 = (tid&1)*8;
  for (int s0=sc*256; s0<sc*256+256; s0+=128){
    const float* lp = lr32 + ((size_t)h*S_ + s0 + row)*16 + c8;
    const float* rp = rsd  + ((size_t)bh*S_ + s0 + row)*64 + dblk*16 + c8;
    float4 l0 = *(const float4*)lp, l1 = *(const float4*)(lp+4);
    float4 r0 = *(const float4*)rp, r1 = *(const float4*)(rp+4);
    *(float4*)&lr_s[row][c8]   = l0; *(float4*)&lr_s[row][c8+4] = l1;
    *(float4*)&rs[row][c8]     = r0; *(float4*)&rs[row][c8+4]   = r1;
    __syncthreads();
    #pragma unroll 8
    for (int ss=0; ss<128; ss++) acc += lr_s[ss][r]*rs[ss][dc];
    __syncthreads();
  }
  rbuf[((size_t)(sc*32+bh)*16 + r)*64 + dblk*16 + dc] = acc;
}

// fused: resid = v - R0 - R1 - lam*alpha (written), partials from resid
__global__ __launch_bounds__(256) void reduce_f_k(
    const float* __restrict__ lr32, const float* __restrict__ v32,
    const float* __restrict__ alpha, const float* __restrict__ Rp,
    const float* __restrict__ lmp,
    float* __restrict__ resid, float* __restrict__ rbuf)
{
  int dblk = blockIdx.x, bh = blockIdx.y, sc = blockIdx.z, h = bh&15;
  int tid = threadIdx.x, r = tid>>4, dc = tid&15;
  float lam = softplus_(lmp[0]) + 1e-6f;
  __shared__ __align__(16) float lr_s[128][20];
  __shared__ __align__(16) float rs[128][20];
  float acc = 0.f;
  int row = tid>>1, c8 = (tid&1)*8;
  const float* R1 = Rp + (size_t)BH_*S_*64;
  for (int s0=sc*256; s0<sc*256+256; s0+=128){
    size_t gbase = ((size_t)bh*S_ + s0 + row)*64 + dblk*16 + c8;
    const float* lp = lr32 + ((size_t)h*S_ + s0 + row)*16 + c8;
    float4 l0 = *(const float4*)lp, l1 = *(const float4*)(lp+4);
    *(float4*)&lr_s[row][c8]   = l0; *(float4*)&lr_s[row][c8+4] = l1;
    float4 vv0 = *(const float4*)(v32+gbase),   vv1 = *(const float4*)(v32+gbase+4);
    float4 p0  = *(const float4*)(Rp+gbase),    p1  = *(const float4*)(Rp+gbase+4);
    float4 q0  = *(const float4*)(R1+gbase),    q1  = *(const float4*)(R1+gbase+4);
    float4 a0  = *(const float4*)(alpha+gbase), a1  = *(const float4*)(alpha+gbase+4);
    float4 rv0, rv1;
    rv0.x = vv0.x - p0.x - q0.x - lam*a0.x;
    rv0.y = vv0.y - p0.y - q0.y - lam*a0.y;
    rv0.z = vv0.z - p0.z - q0.z - lam*a0.z;
    rv0.w = vv0.w - p0.w - q0.w - lam*a0.w;
    rv1.x = vv1.x - p1.x - q1.x - lam*a1.x;
    rv1.y = vv1.y - p1.y - q1.y - lam*a1.y;
    rv1.z = vv1.z - p1.z - q1.z - lam*a1.z;
    rv1.w = vv1.w - p1.w - q1.w - lam*a1.w;
    *(float4*)(resid+gbase)   = rv0;
    *(float4*)(resid+gbase+4) = rv1;
    *(float4*)&rs[row][c8]    = rv0;
    *(float4*)&rs[row][c8+4]  = rv1;
    __syncthreads();
    #pragma unroll 8
    for (int ss=0; ss<128; ss++) acc += lr_s[ss][r]*rs[ss][dc];
    __syncthreads();
  }
  rbuf[((size_t)(sc*32+bh)*16 + r)*64 + dblk*16 + dc] = acc;
}

// alpha = clip(alpha + dp*resid + lr@t), t = sum of 8 rbuf partials
__global__ __launch_bounds__(256) void update_k(
    const float* __restrict__ rsd, const float* __restrict__ alpha_in, int alpha_zero,
    const float* __restrict__ lr32, const float* __restrict__ rbuf,
    const float* __restrict__ dpp,
    float* __restrict__ alpha_out, f16* __restrict__ alphaT)
{
  int sblk = blockIdx.x, bh = blockIdx.y, h = bh&15, s0 = sblk*64;
  int tid = threadIdx.x;
  __shared__ __align__(16) float tb_s[16][64];
  __shared__ __align__(16) float lr_s[64][20];
  __shared__ float dp_s[64];
  __shared__ __align__(16) f16 at_s[64][72];
  {
    float4 t4 = {0.f,0.f,0.f,0.f};
    #pragma unroll
    for (int sc=0; sc<8; sc++){
      float4 p4 = *(const float4*)(rbuf + (size_t)(sc*32+bh)*1024 + tid*4);
      t4.x += p4.x; t4.y += p4.y; t4.z += p4.z; t4.w += p4.w;
    }
    *(float4*)&((float*)tb_s)[tid*4] = t4;
    int row = tid>>2, c4 = (tid&3)*4;
    float4 l4 = *(const float4*)(lr32 + ((size_t)h*S_ + s0 + row)*16 + c4);
    *(float4*)&lr_s[row][c4] = l4;
    if (tid < 64) dp_s[tid] = dpp[(size_t)bh*S_ + s0 + tid];
  }
  __syncthreads();
  #pragma unroll
  for (int i=0;i<16;i++){
    int idx = i*256 + tid;
    int sl = idx>>6, dd = idx&63;
    size_t gi = ((size_t)bh*S_ + s0 + sl)*64 + dd;
    float rv = rsd[gi];
    float av = alpha_zero ? 0.f : alpha_in[gi];
    float acc = av + dp_s[sl]*rv;
    #pragma unroll
    for (int rr=0; rr<16; rr++) acc += lr_s[sl][rr]*tb_s[rr][dd];
    acc = fminf(fmaxf(acc, -10.f), 10.f);
    alpha_out[gi] = acc;
    at_s[dd][sl] = (f16)acc;
  }
  __syncthreads();
  int dd = tid>>2, c16 = (tid&3)*16;
  f16* dst = alphaT + ((size_t)bh*64 + dd)*S_ + s0 + c16;
  *(f16x8*)dst     = *(const f16x8*)&at_s[dd][c16];
  *(f16x8*)(dst+8) = *(const f16x8*)&at_s[dd][c16+8];
}

// ---------------------------------------------------------------------------
extern "C" void kernel_launch(void* const* d_in, const int* in_sizes, int n_in,
                              void* d_out, int out_size, void* d_ws, size_t ws_size,
                              hipStream_t stream)
{
  const float* x   = (const float*)d_in[0];
  const float* wq  = (const float*)d_in[1];
  const float* wk  = (const float*)d_in[2];
  const float* wv  = (const float*)d_in[3];
  const float* wo  = (const float*)d_in[4];
  const float* bwp = (const float*)d_in[5];
  const float* dsp = (const float*)d_in[6];
  const float* rgp = (const float*)d_in[7];
  const float* pos = (const float*)d_in[8];
  const float* hpj = (const float*)d_in[9];
  const float* lmp = (const float*)d_in[10];
  float* outp = (float*)d_out;

  char* base = (char*)d_ws;
  size_t off = 0;
  auto carve = [&](size_t bytes)->char* {
    char* p = base + off; off += (bytes + 255) & ~(size_t)255; return p;
  };
  f16*   x16    = (f16*)  carve((size_t)4096*1024*2);     // 8 MB
  f16*   wqkv16 = (f16*)  carve((size_t)3072*1024*2);     // 6 MB
  f16*   wo16   = (f16*)  carve((size_t)1024*1024*2);     // 2 MB
  f16*   q16    = (f16*)  carve((size_t)BH_*S_*64*2);     // 8 MB
  f16*   k16    = (f16*)  carve((size_t)BH_*S_*64*2);     // 8 MB
  float* v32    = (float*)carve((size_t)BH_*S_*64*4);     // 16 MB
  float* alpha  = (float*)carve((size_t)BH_*S_*64*4);     // 16 MB
  f16*   alphaT = (f16*)  carve((size_t)BH_*64*S_*2);     // 8 MB
  float* resid  = (float*)carve((size_t)BH_*S_*64*4);     // 16 MB
  float* Rp     = (float*)carve((size_t)2*BH_*S_*64*4);   // 32 MB
  f16*   y16    = (f16*)  carve((size_t)4096*1024*2);     // 8 MB
  float* bs     = (float*)carve((size_t)BH_*S_*4);
  float* ct     = (float*)carve((size_t)BH_*S_*4);
  float* dp     = (float*)carve((size_t)BH_*S_*4);
  float* lr32   = (float*)carve((size_t)H_*S_*16*4);      // 2 MB
  float* rbuf   = (float*)carve((size_t)8*BH_*16*64*4);   // 2 MB

  // f32 -> f16 conversions
  cvt_k<<<2048,256,0,stream>>>(x,  x16,               4096*1024/8);
  cvt_k<<< 512,256,0,stream>>>(wq, wqkv16,            1024*1024/8);
  cvt_k<<< 512,256,0,stream>>>(wk, wqkv16+1024*1024,  1024*1024/8);
  cvt_k<<< 512,256,0,stream>>>(wv, wqkv16+2*1024*1024,1024*1024/8);
  cvt_k<<< 512,256,0,stream>>>(wo, wo16,              1024*1024/8);
  // fused QKV projection
  gemm16_k<<<768,256,0,stream>>>(x16, wqkv16, q16, k16, v32, nullptr, 0);
  stats_k<<<256,256,0,stream>>>(q16,k16,bwp,dsp,rgp,bs,ct,dp);
  lr_k<<<2048,256,0,stream>>>(pos,hpj,lr32);
  // iteration 1: alpha=0 -> residual = v
  reduce_t_k<<<dim3(4,32,8),256,0,stream>>>(lr32, v32, rbuf);
  update_k<<<dim3(32,32),256,0,stream>>>(v32, alpha, 1, lr32, rbuf, dp, alpha, alphaT);
  // iterations 2..8
  for (int it=1; it<8; ++it){
    apply_k<<<512,512,0,stream>>>(q16,k16,alphaT,bs,ct,bwp,Rp);
    reduce_f_k<<<dim3(4,32,8),256,0,stream>>>(lr32, v32, alpha, Rp, lmp, resid, rbuf);
    update_k<<<dim3(32,32),256,0,stream>>>(resid, alpha, 0, lr32, rbuf, dp, alpha, alphaT);
  }
  // final: out = K @ alpha, then output projection
  apply_k<<<512,512,0,stream>>>(q16,k16,alphaT,bs,ct,bwp,Rp);
  combine_y_k<<<2048,256,0,stream>>>(Rp, y16);
  gemm16_k<<<256,256,0,stream>>>(y16, wo16, nullptr, nullptr, nullptr, outp, 1);
}

// Round 10
// 787.292 us; speedup vs baseline: 1.1171x; 1.0796x over previous
//
#include <hip/hip_runtime.h>

typedef _Float16 f16;
typedef _Float16 f16x2 __attribute__((ext_vector_type(2)));
typedef _Float16 f16x4 __attribute__((ext_vector_type(4)));
typedef _Float16 f16x8 __attribute__((ext_vector_type(8)));
typedef float f32x4 __attribute__((ext_vector_type(4)));

#define DEVI static __device__ __forceinline__

constexpr int S_  = 2048;
constexpr int H_  = 16;
constexpr int BH_ = 32;   // B*H

DEVI float softplus_(float x){ return logf(1.0f + expf(x)); }
DEVI float exp2_(float x){ return __builtin_amdgcn_exp2f(x); }

DEVI f16x2 cvt2(float a, float b){
  return __builtin_bit_cast(f16x2, __builtin_amdgcn_cvt_pkrtz(a, b));
}

DEVI f16x8 pack8(float4 a, float4 b){
  f16x2 p0 = cvt2(a.x, a.y);
  f16x2 p1 = cvt2(a.z, a.w);
  f16x2 p2 = cvt2(b.x, b.y);
  f16x2 p3 = cvt2(b.z, b.w);
  f16x8 o;
  o[0]=p0[0]; o[1]=p0[1]; o[2]=p1[0]; o[3]=p1[1];
  o[4]=p2[0]; o[5]=p2[1]; o[6]=p3[0]; o[7]=p3[1];
  return o;
}

DEVI void g2l16(const f16* g, f16* l){
  __builtin_amdgcn_global_load_lds(
      (const __attribute__((address_space(1))) void*)(g),
      (__attribute__((address_space(3))) void*)(l), 16, 0, 0);
}

// f32 -> f16 convert, 8 elems/thread
__global__ __launch_bounds__(256) void cvt_k(
    const float* __restrict__ src, f16* __restrict__ dst, int n8)
{
  int i = blockIdx.x*256 + threadIdx.x;
  if (i < n8){
    const float* s = src + (size_t)i*8;
    float4 a = *(const float4*)s, b = *(const float4*)(s+4);
    *(f16x8*)(dst + (size_t)i*8) = pack8(a,b);
  }
}

// ---------------------------------------------------------------------------
// f16 GEMM, BK=64, XCD-swizzled 1D grid, XOR-swizzled LDS (via swizzled
// global source + swizzled read; LDS write stays linear for global_load_lds).
// mode 0: grid 768 (32m x 24n), fused QKV   mode 1: grid 256 (32m x 8n)
// ---------------------------------------------------------------------------
__global__ __launch_bounds__(256) void gemm16_k(
    const f16* __restrict__ A, const f16* __restrict__ W,
    f16* __restrict__ q16, f16* __restrict__ k16, float* __restrict__ v32,
    float* __restrict__ o32f, int mode)
{
  constexpr int K = 1024;
  int id = blockIdx.x;
  int xcd = id & 7, w = id >> 3;
  int gm, gn;
  if (mode==0){ gm = (xcd&3)*8 + w/12; gn = (xcd>>2)*12 + w%12; }
  else        { gm = (xcd&3)*8 + w/4;  gn = (xcd>>2)*4  + (w&3); }
  int m0 = gm*128, n0 = gn*128;

  int tid = threadIdx.x, wave = tid>>6, lane = tid&63, lr_ = lane&15, lg = lane>>4;
  int wm = (wave&1)*64, wn = (wave>>1)*64;
  __shared__ __align__(16) f16 As[128*64];
  __shared__ __align__(16) f16 Ws[128*64];
  f32x4 acc[4][4];
  #pragma unroll
  for (int a=0;a<4;a++)
    #pragma unroll
    for (int b=0;b<4;b++) acc[a][b] = (f32x4){0.f,0.f,0.f,0.f};

  // staging: source column chunk XOR-swizzled by row; LDS dest linear
  const f16 *ap[4], *wp[4]; f16 *la[4], *lw[4];
  #pragma unroll
  for (int c=0;c<4;c++){
    int q = tid + c*256;
    int r = q>>3, cc = q&7;
    int gcol = (cc ^ (r&7))*8;
    ap[c] = A + (size_t)(m0+r)*K + gcol;
    wp[c] = W + (size_t)(n0+r)*K + gcol;
    la[c] = &As[q*8];
    lw[c] = &Ws[q*8];
  }

  for (int kt=0; kt<K; kt+=64){
    #pragma unroll
    for (int c=0;c<4;c++){ g2l16(ap[c]+kt, la[c]); g2l16(wp[c]+kt, lw[c]); }
    __syncthreads();
    #pragma unroll
    for (int ks=0; ks<2; ks++){
      f16x8 af[4], bf[4];
      #pragma unroll
      for (int mf=0;mf<4;mf++){
        int row = wm+mf*16+lr_;
        af[mf] = *(const f16x8*)&As[row*64 + ((ks*4+lg) ^ (row&7))*8];
      }
      #pragma unroll
      for (int nf=0;nf<4;nf++){
        int row = wn+nf*16+lr_;
        bf[nf] = *(const f16x8*)&Ws[row*64 + ((ks*4+lg) ^ (row&7))*8];
      }
      #pragma unroll
      for (int mf=0;mf<4;mf++)
        #pragma unroll
        for (int nf=0;nf<4;nf++)
          acc[mf][nf] = __builtin_amdgcn_mfma_f32_16x16x32_f16(af[mf], bf[nf], acc[mf][nf], 0,0,0);
    }
    __syncthreads();
  }
  #pragma unroll
  for (int mf=0;mf<4;mf++)
    #pragma unroll
    for (int nf=0;nf<4;nf++)
      #pragma unroll
      for (int rg=0;rg<4;rg++){
        int grow = m0+wm+mf*16+lg*4+rg;
        int gcol = n0+wn+nf*16+lr_;
        float vv = acc[mf][nf][rg];
        if (mode==0){
          int mat = gcol>>10, col = gcol&1023;
          int b = grow>>11, s = grow&2047, hh = col>>6, d2 = col&63;
          size_t gi = (((size_t)(b*16+hh))*S_ + s)*64 + d2;
          if (mat==0)      q16[gi] = (f16)vv;
          else if (mat==1) k16[gi] = (f16)vv;
          else             v32[gi] = vv;
        } else {
          o32f[(size_t)grow*1024 + gcol] = vv;
        }
      }
}

// ---------------------------------------------------------------------------
__global__ __launch_bounds__(256) void stats_k(
    const f16* __restrict__ q16, const f16* __restrict__ k16,
    const float* __restrict__ bwp, const float* __restrict__ dsp, const float* __restrict__ rgp,
    float* __restrict__ bs, float* __restrict__ ct, float* __restrict__ dp)
{
  int g = blockIdx.x*256 + threadIdx.x;
  int h = (g>>11)&15;
  float bw = softplus_(bwp[0]) + 1e-6f;
  float c2 = 1.f/(2.f*bw*bw*0.6931471805599453f);
  const f16* qr = q16 + (size_t)g*64;
  const f16* kr = k16 + (size_t)g*64;
  float qsq=0.f, ksq=0.f, qk=0.f;
  #pragma unroll
  for (int c=0;c<8;c++){
    f16x8 qv = *(const f16x8*)(qr + c*8);
    f16x8 kv = *(const f16x8*)(kr + c*8);
    #pragma unroll
    for (int j=0;j<8;j++){
      float a = (float)qv[j], b = (float)kv[j];
      qsq += a*a; ksq += b*b; qk += a*b;
    }
  }
  bs[g] = -qsq*c2;
  ct[g] = -ksq*c2;
  float dist = fmaxf(qsq + ksq - 2.f*qk, 0.f);
  float kd = exp2_(-dist*c2);
  dp[g] = softplus_(kd)*dsp[h] + rgp[0];
}

// lr[h,s,p] = sum_r pos[s,r]*hp[h,r,p]
__global__ __launch_bounds__(256) void lr_k(
    const float* __restrict__ pos, const float* __restrict__ hpj, float* __restrict__ lr32)
{
  int g = blockIdx.x*256 + threadIdx.x;
  int p = g&15, s = (g>>4)&2047, h = g>>15;
  float acc = 0.f;
  #pragma unroll
  for (int r=0;r<16;r++) acc += pos[s*16+r]*hpj[(h*16+r)*16+p];
  lr32[g] = acc;
}

// ---------------------------------------------------------------------------
// Fused apply v7: in-block t-split. 512 thr = 2 groups x 4 waves.
// Group g streams t in [g*1024, g*1024+1024); each wave owns 64 s-rows.
// Halves combined through LDS; resid (mode 0) / y16 (mode 1) written directly.
// ---------------------------------------------------------------------------
__global__ __launch_bounds__(512,2) void apply_k(
    const f16* __restrict__ q16, const f16* __restrict__ k16,
    const f16* __restrict__ alphaT,
    const float* __restrict__ bs, const float* __restrict__ ct,
    const float* __restrict__ v32, const float* __restrict__ alpha32,
    const float* __restrict__ bwp, const float* __restrict__ lmp,
    float* __restrict__ resid, f16* __restrict__ y16,
    int mode)
{
  int id = blockIdx.x;                       // 256: 4 bh per XCD (L2-resident)
  int bh = ((id&7)<<2) | ((id>>3)&3);
  int s0 = (id>>5)*256;

  float bw = softplus_(bwp[0]) + 1e-6f;
  float c2 = 1.f/(2.f*bw*bw*0.6931471805599453f);
  float acoef = 2.f*c2;

  int tid = threadIdx.x, wave = tid>>6, lane = tid&63, lr_ = lane&15, lg = lane>>4;
  int grp = wave>>2, gw = wave&3;
  int sw = s0 + gw*64;                       // this wave's 64 s-rows (4 x 16)
  int tb = grp*1024;

  f16x8 q0[4], q1[4]; float bsv[4];
  #pragma unroll
  for (int sub=0; sub<4; sub++){
    const f16* qr = q16 + ((size_t)bh*S_ + sw + sub*16 + lr_)*64;
    q0[sub] = *(const f16x8*)(qr + lg*8);
    q1[sub] = *(const f16x8*)(qr + 32 + lg*8);
    bsv[sub] = bs[bh*S_ + sw + sub*16 + lr_];
  }

  __shared__ __align__(16) f16 ks[2][2][64][68];   // [grp][buf], pad 68
  __shared__ __align__(16) f16 at[2][2][64][68];
  __shared__ __align__(16) float cts[2][2][64];
  __shared__ __align__(16) float cmb[256][67];     // combine buffer (pad 67)

  f32x4 racc[4][4];
  #pragma unroll
  for (int sub=0;sub<4;sub++)
    #pragma unroll
    for (int df=0;df<4;df++) racc[sub][df] = (f32x4){0.f,0.f,0.f,0.f};

  // staging: 256 threads/group, 2 chunks each (rows r, r+32)
  int local = tid & 255;
  int srow = local>>3, scol = (local&7)*8;
  const f16* kg = k16    + ((size_t)bh*S_ + srow)*64 + scol;
  const f16* ag = alphaT + ((size_t)bh*64 + srow)*S_ + scol;
  const float* ctb = ct + (size_t)bh*S_;
  int lct = local&63;

  f16x8 kv0,kv1,av0,av1; float ctp;
  auto LOADT = [&](int t0){
    kv0 = *(const f16x8*)(kg + (size_t)t0*64);
    kv1 = *(const f16x8*)(kg + (size_t)t0*64 + 32*64);
    av0 = *(const f16x8*)(ag + t0);
    av1 = *(const f16x8*)(ag + t0 + (size_t)32*S_);
    ctp = ctb[t0 + lct];
  };
  auto STORET = [&](int b){
    *(f16x8*)&ks[grp][b][srow][scol]    = kv0;
    *(f16x8*)&ks[grp][b][srow+32][scol] = kv1;
    *(f16x8*)&at[grp][b][srow][scol]    = av0;
    *(f16x8*)&at[grp][b][srow+32][scol] = av1;
    cts[grp][b][lct] = ctp;                   // 4x redundant per group, benign
  };

  LOADT(tb);
  STORET(0);
  LOADT(tb+64);
  __syncthreads();

  for (int tt=0; tt<16; tt++){
    int b = tt&1;
    if (tt<15) STORET(b^1);
    if (tt<14) LOADT(tb + (tt+2)*64);
    #pragma unroll
    for (int tf=0; tf<4; tf++){
      f16x8 ka0 = *(const f16x8*)&ks[grp][b][tf*16+lr_][lg*8];
      f16x8 ka1 = *(const f16x8*)&ks[grp][b][tf*16+lr_][32+lg*8];
      f32x4 ctv = *(const f32x4*)&cts[grp][b][tf*16 + lg*4];
      f16x4 paf[4];
      #pragma unroll
      for (int sub=0; sub<4; sub++){
        f32x4 sacc = (f32x4){0.f,0.f,0.f,0.f};
        sacc = __builtin_amdgcn_mfma_f32_16x16x32_f16(ka0, q0[sub], sacc, 0,0,0);
        sacc = __builtin_amdgcn_mfma_f32_16x16x32_f16(ka1, q1[sub], sacc, 0,0,0);
        float p0 = exp2_(fminf(fmaf(acoef, sacc[0], bsv[sub] + ctv[0]), 0.f));
        float p1 = exp2_(fminf(fmaf(acoef, sacc[1], bsv[sub] + ctv[1]), 0.f));
        float p2 = exp2_(fminf(fmaf(acoef, sacc[2], bsv[sub] + ctv[2]), 0.f));
        float p3 = exp2_(fminf(fmaf(acoef, sacc[3], bsv[sub] + ctv[3]), 0.f));
        f16x2 lo = cvt2(p0,p1), hi = cvt2(p2,p3);
        paf[sub][0]=lo[0]; paf[sub][1]=lo[1]; paf[sub][2]=hi[0]; paf[sub][3]=hi[1];
      }
      #pragma unroll
      for (int df=0; df<4; df++){
        f16x4 bfr = *(const f16x4*)&at[grp][b][df*16+lr_][tf*16+lg*4];
        #pragma unroll
        for (int sub=0; sub<4; sub++)
          racc[sub][df] = __builtin_amdgcn_mfma_f32_16x16x16f16(paf[sub], bfr, racc[sub][df], 0,0,0);
      }
    }
    __syncthreads();
  }

  // combine halves: group 1 -> LDS, group 0 adds + writes output
  if (grp==1){
    #pragma unroll
    for (int sub=0; sub<4; sub++)
      #pragma unroll
      for (int df=0; df<4; df++)
        #pragma unroll
        for (int rg=0; rg<4; rg++)
          cmb[gw*64 + sub*16 + lg*4 + rg][df*16 + lr_] = racc[sub][df][rg];
  }
  __syncthreads();
  if (grp==0){
    if (mode==0){
      float lam = softplus_(lmp[0]) + 1e-6f;
      #pragma unroll
      for (int sub=0; sub<4; sub++)
        #pragma unroll
        for (int df=0; df<4; df++)
          #pragma unroll
          for (int rg=0; rg<4; rg++){
            int sl = gw*64 + sub*16 + lg*4 + rg;
            int dd = df*16 + lr_;
            size_t gi = ((size_t)bh*S_ + s0 + sl)*64 + dd;
            float rv = racc[sub][df][rg] + cmb[sl][dd];
            resid[gi] = v32[gi] - rv - lam*alpha32[gi];
          }
    } else {
      int b2 = bh>>4, h = bh&15;
      #pragma unroll
      for (int sub=0; sub<4; sub++)
        #pragma unroll
        for (int df=0; df<4; df++)
          #pragma unroll
          for (int rg=0; rg<4; rg++){
            int sl = gw*64 + sub*16 + lg*4 + rg;
            int dd = df*16 + lr_;
            float rv = racc[sub][df][rg] + cmb[sl][dd];
            y16[((size_t)(b2*S_+s0+sl))*1024 + h*64 + dd] = (f16)rv;
          }
    }
  }
}

// rbuf[sc,bh,r,d] = sum_{s in chunk sc} lr[h,s,r]*rsd[bh,s,d]  (8 chunks of 256)
__global__ __launch_bounds__(256) void reduce_t_k(
    const float* __restrict__ lr32, const float* __restrict__ rsd, float* __restrict__ rbuf)
{
  int dblk = blockIdx.x, bh = blockIdx.y, sc = blockIdx.z, h = bh&15;
  int tid = threadIdx.x, r = tid>>4, dc = tid&15;
  __shared__ __align__(16) float lr_s[128][20];
  __shared__ __align__(16) float rs[128][20];
  float acc = 0.f;
  int row = tid>>1, c8 = (tid&1)*8;
  for (int s0=sc*256; s0<sc*256+256; s0+=128){
    const float* lp = lr32 + ((size_t)h*S_ + s0 + row)*16 + c8;
    const float* rp = rsd  + ((size_t)bh*S_ + s0 + row)*64 + dblk*16 + c8;
    float4 l0 = *(const float4*)lp, l1 = *(const float4*)(lp+4);
    float4 r0 = *(const float4*)rp, r1 = *(const float4*)(rp+4);
    *(float4*)&lr_s[row][c8]   = l0; *(float4*)&lr_s[row][c8+4] = l1;
    *(float4*)&rs[row][c8]     = r0; *(float4*)&rs[row][c8+4]   = r1;
    __syncthreads();
    #pragma unroll 8
    for (int ss=0; ss<128; ss++) acc += lr_s[ss][r]*rs[ss][dc];
    __syncthreads();
  }
  rbuf[((size_t)(sc*32+bh)*16 + r)*64 + dblk*16 + dc] = acc;
}

// alpha = clip(alpha + dp*resid + lr@t), t = sum of 8 rbuf partials
__global__ __launch_bounds__(256) void update_k(
    const float* __restrict__ rsd, const float* __restrict__ alpha_in, int alpha_zero,
    const float* __restrict__ lr32, const float* __restrict__ rbuf,
    const float* __restrict__ dpp,
    float* __restrict__ alpha_out, f16* __restrict__ alphaT)
{
  int sblk = blockIdx.x, bh = blockIdx.y, h = bh&15, s0 = sblk*64;
  int tid = threadIdx.x;
  __shared__ __align__(16) float tb_s[16][64];
  __shared__ __align__(16) float lr_s[64][20];
  __shared__ float dp_s[64];
  __shared__ __align__(16) f16 at_s[64][72];
  {
    float4 t4 = {0.f,0.f,0.f,0.f};
    #pragma unroll
    for (int sc=0; sc<8; sc++){
      float4 p4 = *(const float4*)(rbuf + (size_t)(sc*32+bh)*1024 + tid*4);
      t4.x += p4.x; t4.y += p4.y; t4.z += p4.z; t4.w += p4.w;
    }
    *(float4*)&((float*)tb_s)[tid*4] = t4;
    int row = tid>>2, c4 = (tid&3)*4;
    float4 l4 = *(const float4*)(lr32 + ((size_t)h*S_ + s0 + row)*16 + c4);
    *(float4*)&lr_s[row][c4] = l4;
    if (tid < 64) dp_s[tid] = dpp[(size_t)bh*S_ + s0 + tid];
  }
  __syncthreads();
  #pragma unroll
  for (int i=0;i<16;i++){
    int idx = i*256 + tid;
    int sl = idx>>6, dd = idx&63;
    size_t gi = ((size_t)bh*S_ + s0 + sl)*64 + dd;
    float rv = rsd[gi];
    float av = alpha_zero ? 0.f : alpha_in[gi];
    float acc = av + dp_s[sl]*rv;
    #pragma unroll
    for (int rr=0; rr<16; rr++) acc += lr_s[sl][rr]*tb_s[rr][dd];
    acc = fminf(fmaxf(acc, -10.f), 10.f);
    alpha_out[gi] = acc;
    at_s[dd][sl] = (f16)acc;
  }
  __syncthreads();
  int dd = tid>>2, c16 = (tid&3)*16;
  f16* dst = alphaT + ((size_t)bh*64 + dd)*S_ + s0 + c16;
  *(f16x8*)dst     = *(const f16x8*)&at_s[dd][c16];
  *(f16x8*)(dst+8) = *(const f16x8*)&at_s[dd][c16+8];
}

// ---------------------------------------------------------------------------
extern "C" void kernel_launch(void* const* d_in, const int* in_sizes, int n_in,
                              void* d_out, int out_size, void* d_ws, size_t ws_size,
                              hipStream_t stream)
{
  const float* x   = (const float*)d_in[0];
  const float* wq  = (const float*)d_in[1];
  const float* wk  = (const float*)d_in[2];
  const float* wv  = (const float*)d_in[3];
  const float* wo  = (const float*)d_in[4];
  const float* bwp = (const float*)d_in[5];
  const float* dsp = (const float*)d_in[6];
  const float* rgp = (const float*)d_in[7];
  const float* pos = (const float*)d_in[8];
  const float* hpj = (const float*)d_in[9];
  const float* lmp = (const float*)d_in[10];
  float* outp = (float*)d_out;

  char* base = (char*)d_ws;
  size_t off = 0;
  auto carve = [&](size_t bytes)->char* {
    char* p = base + off; off += (bytes + 255) & ~(size_t)255; return p;
  };
  f16*   x16    = (f16*)  carve((size_t)4096*1024*2);     // 8 MB
  f16*   wqkv16 = (f16*)  carve((size_t)3072*1024*2);     // 6 MB
  f16*   wo16   = (f16*)  carve((size_t)1024*1024*2);     // 2 MB
  f16*   q16    = (f16*)  carve((size_t)BH_*S_*64*2);     // 8 MB
  f16*   k16    = (f16*)  carve((size_t)BH_*S_*64*2);     // 8 MB
  float* v32    = (float*)carve((size_t)BH_*S_*64*4);     // 16 MB
  float* alpha  = (float*)carve((size_t)BH_*S_*64*4);     // 16 MB
  f16*   alphaT = (f16*)  carve((size_t)BH_*64*S_*2);     // 8 MB
  float* resid  = (float*)carve((size_t)BH_*S_*64*4);     // 16 MB
  f16*   y16    = (f16*)  carve((size_t)4096*1024*2);     // 8 MB
  float* bs     = (float*)carve((size_t)BH_*S_*4);
  float* ct     = (float*)carve((size_t)BH_*S_*4);
  float* dp     = (float*)carve((size_t)BH_*S_*4);
  float* lr32   = (float*)carve((size_t)H_*S_*16*4);      // 2 MB
  float* rbuf   = (float*)carve((size_t)8*BH_*16*64*4);   // 2 MB

  // f32 -> f16 conversions
  cvt_k<<<2048,256,0,stream>>>(x,  x16,               4096*1024/8);
  cvt_k<<< 512,256,0,stream>>>(wq, wqkv16,            1024*1024/8);
  cvt_k<<< 512,256,0,stream>>>(wk, wqkv16+1024*1024,  1024*1024/8);
  cvt_k<<< 512,256,0,stream>>>(wv, wqkv16+2*1024*1024,1024*1024/8);
  cvt_k<<< 512,256,0,stream>>>(wo, wo16,              1024*1024/8);
  // fused QKV projection
  gemm16_k<<<768,256,0,stream>>>(x16, wqkv16, q16, k16, v32, nullptr, 0);
  stats_k<<<256,256,0,stream>>>(q16,k16,bwp,dsp,rgp,bs,ct,dp);
  lr_k<<<2048,256,0,stream>>>(pos,hpj,lr32);
  // iteration 1: alpha=0 -> residual = v
  reduce_t_k<<<dim3(4,32,8),256,0,stream>>>(lr32, v32, rbuf);
  update_k<<<dim3(32,32),256,0,stream>>>(v32, alpha, 1, lr32, rbuf, dp, alpha, alphaT);
  // iterations 2..8
  for (int it=1; it<8; ++it){
    apply_k<<<256,512,0,stream>>>(q16,k16,alphaT,bs,ct,v32,alpha,bwp,lmp,resid,nullptr,0);
    reduce_t_k<<<dim3(4,32,8),256,0,stream>>>(lr32, resid, rbuf);
    update_k<<<dim3(32,32),256,0,stream>>>(resid, alpha, 0, lr32, rbuf, dp, alpha, alphaT);
  }
  // final: out = K @ alpha, then output projection
  apply_k<<<256,512,0,stream>>>(q16,k16,alphaT,bs,ct,v32,alpha,bwp,lmp,resid,y16,1);
  gemm16_k<<<256,256,0,stream>>>(y16, wo16, nullptr, nullptr, nullptr, outp, 1);
}

// Round 11
// 741.846 us; speedup vs baseline: 1.1855x; 1.0613x over previous
//
#include <hip/hip_runtime.h>

typedef _Float16 f16;
typedef _Float16 f16x2 __attribute__((ext_vector_type(2)));
typedef _Float16 f16x4 __attribute__((ext_vector_type(4)));
typedef _Float16 f16x8 __attribute__((ext_vector_type(8)));
typedef float f32x4 __attribute__((ext_vector_type(4)));

#define DEVI static __device__ __forceinline__

constexpr int S_  = 2048;
constexpr int H_  = 16;
constexpr int BH_ = 32;   // B*H

DEVI float softplus_(float x){ return logf(1.0f + expf(x)); }
DEVI float exp2_(float x){ return __builtin_amdgcn_exp2f(x); }

DEVI f16x2 cvt2(float a, float b){
  return __builtin_bit_cast(f16x2, __builtin_amdgcn_cvt_pkrtz(a, b));
}

DEVI f16x8 pack8(float4 a, float4 b){
  f16x2 p0 = cvt2(a.x, a.y);
  f16x2 p1 = cvt2(a.z, a.w);
  f16x2 p2 = cvt2(b.x, b.y);
  f16x2 p3 = cvt2(b.z, b.w);
  f16x8 o;
  o[0]=p0[0]; o[1]=p0[1]; o[2]=p1[0]; o[3]=p1[1];
  o[4]=p2[0]; o[5]=p2[1]; o[6]=p3[0]; o[7]=p3[1];
  return o;
}

DEVI void g2l16(const f16* g, f16* l){
  __builtin_amdgcn_global_load_lds(
      (const __attribute__((address_space(1))) void*)(g),
      (__attribute__((address_space(3))) void*)(l), 16, 0, 0);
}

// f32 -> f16 convert, 8 elems/thread
__global__ __launch_bounds__(256) void cvt_k(
    const float* __restrict__ src, f16* __restrict__ dst, int n8)
{
  int i = blockIdx.x*256 + threadIdx.x;
  if (i < n8){
    const float* s = src + (size_t)i*8;
    float4 a = *(const float4*)s, b = *(const float4*)(s+4);
    *(f16x8*)(dst + (size_t)i*8) = pack8(a,b);
  }
}

// ---------------------------------------------------------------------------
// f16 GEMM, BK=64, XCD-swizzled 1D grid, XOR-swizzled LDS (swizzled source +
// swizzled read; linear LDS dest for global_load_lds).
// mode 0: grid 768 (32m x 24n), fused QKV   mode 1: grid 256 (32m x 8n)
// ---------------------------------------------------------------------------
__global__ __launch_bounds__(256) void gemm16_k(
    const f16* __restrict__ A, const f16* __restrict__ W,
    f16* __restrict__ q16, f16* __restrict__ k16, float* __restrict__ v32,
    float* __restrict__ o32f, int mode)
{
  constexpr int K = 1024;
  int id = blockIdx.x;
  int xcd = id & 7, w = id >> 3;
  int gm, gn;
  if (mode==0){ gm = (xcd&3)*8 + w/12; gn = (xcd>>2)*12 + w%12; }
  else        { gm = (xcd&3)*8 + w/4;  gn = (xcd>>2)*4  + (w&3); }
  int m0 = gm*128, n0 = gn*128;

  int tid = threadIdx.x, wave = tid>>6, lane = tid&63, lr_ = lane&15, lg = lane>>4;
  int wm = (wave&1)*64, wn = (wave>>1)*64;
  __shared__ __align__(16) f16 As[128*64];
  __shared__ __align__(16) f16 Ws[128*64];
  f32x4 acc[4][4];
  #pragma unroll
  for (int a=0;a<4;a++)
    #pragma unroll
    for (int b=0;b<4;b++) acc[a][b] = (f32x4){0.f,0.f,0.f,0.f};

  const f16 *ap[4], *wp[4]; f16 *la[4], *lw[4];
  #pragma unroll
  for (int c=0;c<4;c++){
    int q = tid + c*256;
    int r = q>>3, cc = q&7;
    int gcol = (cc ^ (r&7))*8;
    ap[c] = A + (size_t)(m0+r)*K + gcol;
    wp[c] = W + (size_t)(n0+r)*K + gcol;
    la[c] = &As[q*8];
    lw[c] = &Ws[q*8];
  }

  for (int kt=0; kt<K; kt+=64){
    #pragma unroll
    for (int c=0;c<4;c++){ g2l16(ap[c]+kt, la[c]); g2l16(wp[c]+kt, lw[c]); }
    __syncthreads();
    #pragma unroll
    for (int ks=0; ks<2; ks++){
      f16x8 af[4], bf[4];
      #pragma unroll
      for (int mf=0;mf<4;mf++){
        int row = wm+mf*16+lr_;
        af[mf] = *(const f16x8*)&As[row*64 + ((ks*4+lg) ^ (row&7))*8];
      }
      #pragma unroll
      for (int nf=0;nf<4;nf++){
        int row = wn+nf*16+lr_;
        bf[nf] = *(const f16x8*)&Ws[row*64 + ((ks*4+lg) ^ (row&7))*8];
      }
      #pragma unroll
      for (int mf=0;mf<4;mf++)
        #pragma unroll
        for (int nf=0;nf<4;nf++)
          acc[mf][nf] = __builtin_amdgcn_mfma_f32_16x16x32_f16(af[mf], bf[nf], acc[mf][nf], 0,0,0);
    }
    __syncthreads();
  }
  #pragma unroll
  for (int mf=0;mf<4;mf++)
    #pragma unroll
    for (int nf=0;nf<4;nf++)
      #pragma unroll
      for (int rg=0;rg<4;rg++){
        int grow = m0+wm+mf*16+lg*4+rg;
        int gcol = n0+wn+nf*16+lr_;
        float vv = acc[mf][nf][rg];
        if (mode==0){
          int mat = gcol>>10, col = gcol&1023;
          int b = grow>>11, s = grow&2047, hh = col>>6, d2 = col&63;
          size_t gi = (((size_t)(b*16+hh))*S_ + s)*64 + d2;
          if (mat==0)      q16[gi] = (f16)vv;
          else if (mat==1) k16[gi] = (f16)vv;
          else             v32[gi] = vv;
        } else {
          o32f[(size_t)grow*1024 + gcol] = vv;
        }
      }
}

// ---------------------------------------------------------------------------
__global__ __launch_bounds__(256) void stats_k(
    const f16* __restrict__ q16, const f16* __restrict__ k16,
    const float* __restrict__ bwp, const float* __restrict__ dsp, const float* __restrict__ rgp,
    float* __restrict__ bs, float* __restrict__ ct, float* __restrict__ dp)
{
  int g = blockIdx.x*256 + threadIdx.x;
  int h = (g>>11)&15;
  float bw = softplus_(bwp[0]) + 1e-6f;
  float c2 = 1.f/(2.f*bw*bw*0.6931471805599453f);
  const f16* qr = q16 + (size_t)g*64;
  const f16* kr = k16 + (size_t)g*64;
  float qsq=0.f, ksq=0.f, qk=0.f;
  #pragma unroll
  for (int c=0;c<8;c++){
    f16x8 qv = *(const f16x8*)(qr + c*8);
    f16x8 kv = *(const f16x8*)(kr + c*8);
    #pragma unroll
    for (int j=0;j<8;j++){
      float a = (float)qv[j], b = (float)kv[j];
      qsq += a*a; ksq += b*b; qk += a*b;
    }
  }
  bs[g] = -qsq*c2;
  ct[g] = -ksq*c2;
  float dist = fmaxf(qsq + ksq - 2.f*qk, 0.f);
  float kd = exp2_(-dist*c2);
  dp[g] = softplus_(kd)*dsp[h] + rgp[0];
}

// lr[h,s,p] = sum_r pos[s,r]*hp[h,r,p]
__global__ __launch_bounds__(256) void lr_k(
    const float* __restrict__ pos, const float* __restrict__ hpj, float* __restrict__ lr32)
{
  int g = blockIdx.x*256 + threadIdx.x;
  int p = g&15, s = (g>>4)&2047, h = g>>15;
  float acc = 0.f;
  #pragma unroll
  for (int r=0;r<16;r++) acc += pos[s*16+r]*hpj[(h*16+r)*16+p];
  lr32[g] = acc;
}

// ---------------------------------------------------------------------------
// Fused apply v8: 1024 thr = 2 t-groups x 8 s-waves x 32 s-rows.
// 16 waves/CU (4/SIMD) — same LDS traffic as v4, double the latency hiding.
// Group g streams t in [g*1024, g*1024+1024). Halves combined via LDS.
// mode 0: resid = v - R - lam*alpha      mode 1: y16 = R
// ---------------------------------------------------------------------------
__global__ __launch_bounds__(1024,4) void apply_k(
    const f16* __restrict__ q16, const f16* __restrict__ k16,
    const f16* __restrict__ alphaT,
    const float* __restrict__ bs, const float* __restrict__ ct,
    const float* __restrict__ v32, const float* __restrict__ alpha32,
    const float* __restrict__ bwp, const float* __restrict__ lmp,
    float* __restrict__ resid, f16* __restrict__ y16,
    int mode)
{
  int id = blockIdx.x;                       // 256: 4 bh per XCD (L2-resident)
  int bh = ((id&7)<<2) | ((id>>3)&3);
  int s0 = (id>>5)*256;

  float bw = softplus_(bwp[0]) + 1e-6f;
  float c2 = 1.f/(2.f*bw*bw*0.6931471805599453f);
  float acoef = 2.f*c2;

  int tid = threadIdx.x, wave = tid>>6, lane = tid&63, lr_ = lane&15, lg = lane>>4;
  int grp = wave>>3, gw = wave&7;
  int sw = s0 + gw*32;                       // this wave's 32 s-rows (2 x 16)
  int tb = grp*1024;

  f16x8 q0[2], q1[2]; float bsv[2];
  #pragma unroll
  for (int sub=0; sub<2; sub++){
    const f16* qr = q16 + ((size_t)bh*S_ + sw + sub*16 + lr_)*64;
    q0[sub] = *(const f16x8*)(qr + lg*8);
    q1[sub] = *(const f16x8*)(qr + 32 + lg*8);
    bsv[sub] = bs[bh*S_ + sw + sub*16 + lr_];
  }

  __shared__ __align__(16) f16 ks[2][2][64][68];   // [grp][buf], pad 68
  __shared__ __align__(16) f16 at[2][2][64][68];
  __shared__ __align__(16) float cts[2][2][64];
  __shared__ __align__(16) float cmb[256][67];     // combine buffer

  f32x4 racc[2][4];
  #pragma unroll
  for (int sub=0;sub<2;sub++)
    #pragma unroll
    for (int df=0;df<4;df++) racc[sub][df] = (f32x4){0.f,0.f,0.f,0.f};

  // staging: 512 threads/group, 1 chunk each of ks and at per tile
  int local = tid & 511;
  int srow = local>>3, scol = (local&7)*8;
  const f16* kg = k16    + ((size_t)bh*S_ + srow)*64 + scol;
  const f16* ag = alphaT + ((size_t)bh*64 + srow)*S_ + scol;
  const float* ctb = ct + (size_t)bh*S_;
  int lct = local&63;

  f16x8 kv, av; float ctp;
  auto LOADT = [&](int t0){
    kv  = *(const f16x8*)(kg + (size_t)t0*64);
    av  = *(const f16x8*)(ag + t0);
    ctp = ctb[t0 + lct];
  };
  auto STORET = [&](int b){
    *(f16x8*)&ks[grp][b][srow][scol] = kv;
    *(f16x8*)&at[grp][b][srow][scol] = av;
    cts[grp][b][lct] = ctp;                   // redundant across waves, benign
  };

  LOADT(tb);
  STORET(0);
  LOADT(tb+64);
  __syncthreads();

  for (int tt=0; tt<16; tt++){
    int b = tt&1;
    if (tt<15) STORET(b^1);
    if (tt<14) LOADT(tb + (tt+2)*64);
    #pragma unroll
    for (int tf=0; tf<4; tf++){
      f16x8 ka0 = *(const f16x8*)&ks[grp][b][tf*16+lr_][lg*8];
      f16x8 ka1 = *(const f16x8*)&ks[grp][b][tf*16+lr_][32+lg*8];
      f32x4 ctv = *(const f32x4*)&cts[grp][b][tf*16 + lg*4];
      f16x4 paf[2];
      #pragma unroll
      for (int sub=0; sub<2; sub++){
        f32x4 sacc = (f32x4){0.f,0.f,0.f,0.f};
        sacc = __builtin_amdgcn_mfma_f32_16x16x32_f16(ka0, q0[sub], sacc, 0,0,0);
        sacc = __builtin_amdgcn_mfma_f32_16x16x32_f16(ka1, q1[sub], sacc, 0,0,0);
        // exponent <= ~1e-6 by construction (consistent f16 q/k) -> no clamp
        float p0 = exp2_(fmaf(acoef, sacc[0], bsv[sub] + ctv[0]));
        float p1 = exp2_(fmaf(acoef, sacc[1], bsv[sub] + ctv[1]));
        float p2 = exp2_(fmaf(acoef, sacc[2], bsv[sub] + ctv[2]));
        float p3 = exp2_(fmaf(acoef, sacc[3], bsv[sub] + ctv[3]));
        f16x2 lo = cvt2(p0,p1), hi = cvt2(p2,p3);
        paf[sub][0]=lo[0]; paf[sub][1]=lo[1]; paf[sub][2]=hi[0]; paf[sub][3]=hi[1];
      }
      #pragma unroll
      for (int df=0; df<4; df++){
        f16x4 bfr = *(const f16x4*)&at[grp][b][df*16+lr_][tf*16+lg*4];
        #pragma unroll
        for (int sub=0; sub<2; sub++)
          racc[sub][df] = __builtin_amdgcn_mfma_f32_16x16x16f16(paf[sub], bfr, racc[sub][df], 0,0,0);
      }
    }
    __syncthreads();
  }

  // combine halves: group 1 -> LDS, group 0 adds + writes output
  if (grp==1){
    #pragma unroll
    for (int sub=0; sub<2; sub++)
      #pragma unroll
      for (int df=0; df<4; df++)
        #pragma unroll
        for (int rg=0; rg<4; rg++)
          cmb[gw*32 + sub*16 + lg*4 + rg][df*16 + lr_] = racc[sub][df][rg];
  }
  __syncthreads();
  if (grp==0){
    if (mode==0){
      float lam = softplus_(lmp[0]) + 1e-6f;
      #pragma unroll
      for (int sub=0; sub<2; sub++)
        #pragma unroll
        for (int df=0; df<4; df++)
          #pragma unroll
          for (int rg=0; rg<4; rg++){
            int sl = gw*32 + sub*16 + lg*4 + rg;
            int dd = df*16 + lr_;
            size_t gi = ((size_t)bh*S_ + s0 + sl)*64 + dd;
            float rv = racc[sub][df][rg] + cmb[sl][dd];
            resid[gi] = v32[gi] - rv - lam*alpha32[gi];
          }
    } else {
      int b2 = bh>>4, h = bh&15;
      #pragma unroll
      for (int sub=0; sub<2; sub++)
        #pragma unroll
        for (int df=0; df<4; df++)
          #pragma unroll
          for (int rg=0; rg<4; rg++){
            int sl = gw*32 + sub*16 + lg*4 + rg;
            int dd = df*16 + lr_;
            float rv = racc[sub][df][rg] + cmb[sl][dd];
            y16[((size_t)(b2*S_+s0+sl))*1024 + h*64 + dd] = (f16)rv;
          }
    }
  }
}

// rbuf[sc,bh,r,d] = sum_{s in chunk sc} lr[h,s,r]*rsd[bh,s,d]  (8 chunks of 256)
__global__ __launch_bounds__(256) void reduce_t_k(
    const float* __restrict__ lr32, const float* __restrict__ rsd, float* __restrict__ rbuf)
{
  int dblk = blockIdx.x, bh = blockIdx.y, sc = blockIdx.z, h = bh&15;
  int tid = threadIdx.x, r = tid>>4, dc = tid&15;
  __shared__ __align__(16) float lr_s[128][20];
  __shared__ __align__(16) float rs[128][20];
  float acc = 0.f;
  int row = tid>>1, c8 = (tid&1)*8;
  for (int s0=sc*256; s0<sc*256+256; s0+=128){
    const float* lp = lr32 + ((size_t)h*S_ + s0 + row)*16 + c8;
    const float* rp = rsd  + ((size_t)bh*S_ + s0 + row)*64 + dblk*16 + c8;
    float4 l0 = *(const float4*)lp, l1 = *(const float4*)(lp+4);
    float4 r0 = *(const float4*)rp, r1 = *(const float4*)(rp+4);
    *(float4*)&lr_s[row][c8]   = l0; *(float4*)&lr_s[row][c8+4] = l1;
    *(float4*)&rs[row][c8]     = r0; *(float4*)&rs[row][c8+4]   = r1;
    __syncthreads();
    #pragma unroll 8
    for (int ss=0; ss<128; ss++) acc += lr_s[ss][r]*rs[ss][dc];
    __syncthreads();
  }
  rbuf[((size_t)(sc*32+bh)*16 + r)*64 + dblk*16 + dc] = acc;
}

// alpha = clip(alpha + dp*resid + lr@t), t = sum of 8 rbuf partials
__global__ __launch_bounds__(256) void update_k(
    const float* __restrict__ rsd, const float* __restrict__ alpha_in, int alpha_zero,
    const float* __restrict__ lr32, const float* __restrict__ rbuf,
    const float* __restrict__ dpp,
    float* __restrict__ alpha_out, f16* __restrict__ alphaT)
{
  int sblk = blockIdx.x, bh = blockIdx.y, h = bh&15, s0 = sblk*64;
  int tid = threadIdx.x;
  __shared__ __align__(16) float tb_s[16][64];
  __shared__ __align__(16) float lr_s[64][20];
  __shared__ float dp_s[64];
  __shared__ __align__(16) f16 at_s[64][72];
  {
    float4 t4 = {0.f,0.f,0.f,0.f};
    #pragma unroll
    for (int sc=0; sc<8; sc++){
      float4 p4 = *(const float4*)(rbuf + (size_t)(sc*32+bh)*1024 + tid*4);
      t4.x += p4.x; t4.y += p4.y; t4.z += p4.z; t4.w += p4.w;
    }
    *(float4*)&((float*)tb_s)[tid*4] = t4;
    int row = tid>>2, c4 = (tid&3)*4;
    float4 l4 = *(const float4*)(lr32 + ((size_t)h*S_ + s0 + row)*16 + c4);
    *(float4*)&lr_s[row][c4] = l4;
    if (tid < 64) dp_s[tid] = dpp[(size_t)bh*S_ + s0 + tid];
  }
  __syncthreads();
  #pragma unroll
  for (int i=0;i<16;i++){
    int idx = i*256 + tid;
    int sl = idx>>6, dd = idx&63;
    size_t gi = ((size_t)bh*S_ + s0 + sl)*64 + dd;
    float rv = rsd[gi];
    float av = alpha_zero ? 0.f : alpha_in[gi];
    float acc = av + dp_s[sl]*rv;
    #pragma unroll
    for (int rr=0; rr<16; rr++) acc += lr_s[sl][rr]*tb_s[rr][dd];
    acc = fminf(fmaxf(acc, -10.f), 10.f);
    alpha_out[gi] = acc;
    at_s[dd][sl] = (f16)acc;
  }
  __syncthreads();
  int dd = tid>>2, c16 = (tid&3)*16;
  f16* dst = alphaT + ((size_t)bh*64 + dd)*S_ + s0 + c16;
  *(f16x8*)dst     = *(const f16x8*)&at_s[dd][c16];
  *(f16x8*)(dst+8) = *(const f16x8*)&at_s[dd][c16+8];
}

// ---------------------------------------------------------------------------
extern "C" void kernel_launch(void* const* d_in, const int* in_sizes, int n_in,
                              void* d_out, int out_size, void* d_ws, size_t ws_size,
                              hipStream_t stream)
{
  const float* x   = (const float*)d_in[0];
  const float* wq  = (const float*)d_in[1];
  const float* wk  = (const float*)d_in[2];
  const float* wv  = (const float*)d_in[3];
  const float* wo  = (const float*)d_in[4];
  const float* bwp = (const float*)d_in[5];
  const float* dsp = (const float*)d_in[6];
  const float* rgp = (const float*)d_in[7];
  const float* pos = (const float*)d_in[8];
  const float* hpj = (const float*)d_in[9];
  const float* lmp = (const float*)d_in[10];
  float* outp = (float*)d_out;

  char* base = (char*)d_ws;
  size_t off = 0;
  auto carve = [&](size_t bytes)->char* {
    char* p = base + off; off += (bytes + 255) & ~(size_t)255; return p;
  };
  f16*   x16    = (f16*)  carve((size_t)4096*1024*2);     // 8 MB
  f16*   wqkv16 = (f16*)  carve((size_t)3072*1024*2);     // 6 MB
  f16*   wo16   = (f16*)  carve((size_t)1024*1024*2);     // 2 MB
  f16*   q16    = (f16*)  carve((size_t)BH_*S_*64*2);     // 8 MB
  f16*   k16    = (f16*)  carve((size_t)BH_*S_*64*2);     // 8 MB
  float* v32    = (float*)carve((size_t)BH_*S_*64*4);     // 16 MB
  float* alpha  = (float*)carve((size_t)BH_*S_*64*4);     // 16 MB
  f16*   alphaT = (f16*)  carve((size_t)BH_*64*S_*2);     // 8 MB
  float* resid  = (float*)carve((size_t)BH_*S_*64*4);     // 16 MB
  f16*   y16    = (f16*)  carve((size_t)4096*1024*2);     // 8 MB
  float* bs     = (float*)carve((size_t)BH_*S_*4);
  float* ct     = (float*)carve((size_t)BH_*S_*4);
  float* dp     = (float*)carve((size_t)BH_*S_*4);
  float* lr32   = (float*)carve((size_t)H_*S_*16*4);      // 2 MB
  float* rbuf   = (float*)carve((size_t)8*BH_*16*64*4);   // 2 MB

  // f32 -> f16 conversions
  cvt_k<<<2048,256,0,stream>>>(x,  x16,               4096*1024/8);
  cvt_k<<< 512,256,0,stream>>>(wq, wqkv16,            1024*1024/8);
  cvt_k<<< 512,256,0,stream>>>(wk, wqkv16+1024*1024,  1024*1024/8);
  cvt_k<<< 512,256,0,stream>>>(wv, wqkv16+2*1024*1024,1024*1024/8);
  cvt_k<<< 512,256,0,stream>>>(wo, wo16,              1024*1024/8);
  // fused QKV projection
  gemm16_k<<<768,256,0,stream>>>(x16, wqkv16, q16, k16, v32, nullptr, 0);
  stats_k<<<256,256,0,stream>>>(q16,k16,bwp,dsp,rgp,bs,ct,dp);
  lr_k<<<2048,256,0,stream>>>(pos,hpj,lr32);
  // iteration 1: alpha=0 -> residual = v
  reduce_t_k<<<dim3(4,32,8),256,0,stream>>>(lr32, v32, rbuf);
  update_k<<<dim3(32,32),256,0,stream>>>(v32, alpha, 1, lr32, rbuf, dp, alpha, alphaT);
  // iterations 2..8
  for (int it=1; it<8; ++it){
    apply_k<<<256,1024,0,stream>>>(q16,k16,alphaT,bs,ct,v32,alpha,bwp,lmp,resid,nullptr,0);
    reduce_t_k<<<dim3(4,32,8),256,0,stream>>>(lr32, resid, rbuf);
    update_k<<<dim3(32,32),256,0,stream>>>(resid, alpha, 0, lr32, rbuf, dp, alpha, alphaT);
  }
  // final: out = K @ alpha, then output projection
  apply_k<<<256,1024,0,stream>>>(q16,k16,alphaT,bs,ct,v32,alpha,bwp,lmp,resid,y16,1);
  gemm16_k<<<256,256,0,stream>>>(y16, wo16, nullptr, nullptr, nullptr, outp, 1);
}

// Round 12
// 699.173 us; speedup vs baseline: 1.2579x; 1.0610x over previous
//
#include <hip/hip_runtime.h>

typedef _Float16 f16;
typedef _Float16 f16x2 __attribute__((ext_vector_type(2)));
typedef _Float16 f16x4 __attribute__((ext_vector_type(4)));
typedef _Float16 f16x8 __attribute__((ext_vector_type(8)));
typedef float f32x4 __attribute__((ext_vector_type(4)));

#define DEVI static __device__ __forceinline__

constexpr int S_  = 2048;
constexpr int H_  = 16;
constexpr int BH_ = 32;   // B*H

DEVI float softplus_(float x){ return logf(1.0f + expf(x)); }
DEVI float exp2_(float x){ return __builtin_amdgcn_exp2f(x); }

DEVI f16x2 cvt2(float a, float b){
  return __builtin_bit_cast(f16x2, __builtin_amdgcn_cvt_pkrtz(a, b));
}

DEVI f16x8 pack8(float4 a, float4 b){
  f16x2 p0 = cvt2(a.x, a.y);
  f16x2 p1 = cvt2(a.z, a.w);
  f16x2 p2 = cvt2(b.x, b.y);
  f16x2 p3 = cvt2(b.z, b.w);
  f16x8 o;
  o[0]=p0[0]; o[1]=p0[1]; o[2]=p1[0]; o[3]=p1[1];
  o[4]=p2[0]; o[5]=p2[1]; o[6]=p3[0]; o[7]=p3[1];
  return o;
}

DEVI void g2l16(const f16* g, f16* l){
  __builtin_amdgcn_global_load_lds(
      (const __attribute__((address_space(1))) void*)(g),
      (__attribute__((address_space(3))) void*)(l), 16, 0, 0);
}

// f32 -> f16 convert, 8 elems/thread
__global__ __launch_bounds__(256) void cvt_k(
    const float* __restrict__ src, f16* __restrict__ dst, int n8)
{
  int i = blockIdx.x*256 + threadIdx.x;
  if (i < n8){
    const float* s = src + (size_t)i*8;
    float4 a = *(const float4*)s, b = *(const float4*)(s+4);
    *(f16x8*)(dst + (size_t)i*8) = pack8(a,b);
  }
}

// ---------------------------------------------------------------------------
// f16 GEMM, BK=64, XCD-swizzled 1D grid, XOR-swizzled LDS (swizzled source +
// swizzled read; linear LDS dest for global_load_lds).
// mode 0: grid 768 (32m x 24n), fused QKV   mode 1: grid 256 (32m x 8n)
// ---------------------------------------------------------------------------
__global__ __launch_bounds__(256) void gemm16_k(
    const f16* __restrict__ A, const f16* __restrict__ W,
    f16* __restrict__ q16, f16* __restrict__ k16, float* __restrict__ v32,
    float* __restrict__ o32f, int mode)
{
  constexpr int K = 1024;
  int id = blockIdx.x;
  int xcd = id & 7, w = id >> 3;
  int gm, gn;
  if (mode==0){ gm = (xcd&3)*8 + w/12; gn = (xcd>>2)*12 + w%12; }
  else        { gm = (xcd&3)*8 + w/4;  gn = (xcd>>2)*4  + (w&3); }
  int m0 = gm*128, n0 = gn*128;

  int tid = threadIdx.x, wave = tid>>6, lane = tid&63, lr_ = lane&15, lg = lane>>4;
  int wm = (wave&1)*64, wn = (wave>>1)*64;
  __shared__ __align__(16) f16 As[128*64];
  __shared__ __align__(16) f16 Ws[128*64];
  f32x4 acc[4][4];
  #pragma unroll
  for (int a=0;a<4;a++)
    #pragma unroll
    for (int b=0;b<4;b++) acc[a][b] = (f32x4){0.f,0.f,0.f,0.f};

  const f16 *ap[4], *wp[4]; f16 *la[4], *lw[4];
  #pragma unroll
  for (int c=0;c<4;c++){
    int q = tid + c*256;
    int r = q>>3, cc = q&7;
    int gcol = (cc ^ (r&7))*8;
    ap[c] = A + (size_t)(m0+r)*K + gcol;
    wp[c] = W + (size_t)(n0+r)*K + gcol;
    la[c] = &As[q*8];
    lw[c] = &Ws[q*8];
  }

  for (int kt=0; kt<K; kt+=64){
    #pragma unroll
    for (int c=0;c<4;c++){ g2l16(ap[c]+kt, la[c]); g2l16(wp[c]+kt, lw[c]); }
    __syncthreads();
    #pragma unroll
    for (int ks=0; ks<2; ks++){
      f16x8 af[4], bf[4];
      #pragma unroll
      for (int mf=0;mf<4;mf++){
        int row = wm+mf*16+lr_;
        af[mf] = *(const f16x8*)&As[row*64 + ((ks*4+lg) ^ (row&7))*8];
      }
      #pragma unroll
      for (int nf=0;nf<4;nf++){
        int row = wn+nf*16+lr_;
        bf[nf] = *(const f16x8*)&Ws[row*64 + ((ks*4+lg) ^ (row&7))*8];
      }
      #pragma unroll
      for (int mf=0;mf<4;mf++)
        #pragma unroll
        for (int nf=0;nf<4;nf++)
          acc[mf][nf] = __builtin_amdgcn_mfma_f32_16x16x32_f16(af[mf], bf[nf], acc[mf][nf], 0,0,0);
    }
    __syncthreads();
  }
  #pragma unroll
  for (int mf=0;mf<4;mf++)
    #pragma unroll
    for (int nf=0;nf<4;nf++)
      #pragma unroll
      for (int rg=0;rg<4;rg++){
        int grow = m0+wm+mf*16+lg*4+rg;
        int gcol = n0+wn+nf*16+lr_;
        float vv = acc[mf][nf][rg];
        if (mode==0){
          int mat = gcol>>10, col = gcol&1023;
          int b = grow>>11, s = grow&2047, hh = col>>6, d2 = col&63;
          size_t gi = (((size_t)(b*16+hh))*S_ + s)*64 + d2;
          if (mat==0)      q16[gi] = (f16)vv;
          else if (mat==1) k16[gi] = (f16)vv;
          else             v32[gi] = vv;
        } else {
          o32f[(size_t)grow*1024 + gcol] = vv;
        }
      }
}

// ---------------------------------------------------------------------------
__global__ __launch_bounds__(256) void stats_k(
    const f16* __restrict__ q16, const f16* __restrict__ k16,
    const float* __restrict__ bwp, const float* __restrict__ dsp, const float* __restrict__ rgp,
    float* __restrict__ bs, float* __restrict__ ct, float* __restrict__ dp)
{
  int g = blockIdx.x*256 + threadIdx.x;
  int h = (g>>11)&15;
  float bw = softplus_(bwp[0]) + 1e-6f;
  float c2 = 1.f/(2.f*bw*bw*0.6931471805599453f);
  const f16* qr = q16 + (size_t)g*64;
  const f16* kr = k16 + (size_t)g*64;
  float qsq=0.f, ksq=0.f, qk=0.f;
  #pragma unroll
  for (int c=0;c<8;c++){
    f16x8 qv = *(const f16x8*)(qr + c*8);
    f16x8 kv = *(const f16x8*)(kr + c*8);
    #pragma unroll
    for (int j=0;j<8;j++){
      float a = (float)qv[j], b = (float)kv[j];
      qsq += a*a; ksq += b*b; qk += a*b;
    }
  }
  bs[g] = -qsq*c2;
  ct[g] = -ksq*c2;
  float dist = fmaxf(qsq + ksq - 2.f*qk, 0.f);
  float kd = exp2_(-dist*c2);
  dp[g] = softplus_(kd)*dsp[h] + rgp[0];
}

// lr[h,s,p] = sum_r pos[s,r]*hp[h,r,p]
__global__ __launch_bounds__(256) void lr_k(
    const float* __restrict__ pos, const float* __restrict__ hpj, float* __restrict__ lr32)
{
  int g = blockIdx.x*256 + threadIdx.x;
  int p = g&15, s = (g>>4)&2047, h = g>>15;
  float acc = 0.f;
  #pragma unroll
  for (int r=0;r<16;r++) acc += pos[s*16+r]*hpj[(h*16+r)*16+p];
  lr32[g] = acc;
}

// ---------------------------------------------------------------------------
// Fused apply v9: 1024 thr = 2 t-groups x 8 s-waves x 32 s-rows, 16 waves/CU.
// mode 0: resid = v - R - lam*alpha  AND  rbuf[chunk] = lr^T @ resid (fused,
//         resid from registers -- no global re-read). chunk = s-block (8 total).
// mode 1: y16 = R
// ---------------------------------------------------------------------------
__global__ __launch_bounds__(1024,4) void apply_k(
    const f16* __restrict__ q16, const f16* __restrict__ k16,
    const f16* __restrict__ alphaT,
    const float* __restrict__ bs, const float* __restrict__ ct,
    const float* __restrict__ v32, const float* __restrict__ alpha32,
    const float* __restrict__ bwp, const float* __restrict__ lmp,
    const float* __restrict__ lr32, float* __restrict__ rbuf,
    float* __restrict__ resid, f16* __restrict__ y16,
    int mode)
{
  int id = blockIdx.x;                       // 256: 4 bh per XCD (L2-resident)
  int bh = ((id&7)<<2) | ((id>>3)&3);
  int s0 = (id>>5)*256;

  float bw = softplus_(bwp[0]) + 1e-6f;
  float c2 = 1.f/(2.f*bw*bw*0.6931471805599453f);
  float acoef = 2.f*c2;

  int tid = threadIdx.x, wave = tid>>6, lane = tid&63, lr_ = lane&15, lg = lane>>4;
  int grp = wave>>3, gw = wave&7;
  int sw = s0 + gw*32;                       // this wave's 32 s-rows (2 x 16)
  int tb = grp*1024;

  f16x8 q0[2], q1[2]; float bsv[2];
  #pragma unroll
  for (int sub=0; sub<2; sub++){
    const f16* qr = q16 + ((size_t)bh*S_ + sw + sub*16 + lr_)*64;
    q0[sub] = *(const f16x8*)(qr + lg*8);
    q1[sub] = *(const f16x8*)(qr + 32 + lg*8);
    bsv[sub] = bs[bh*S_ + sw + sub*16 + lr_];
  }

  __shared__ __align__(16) f16 ks[2][2][64][68];   // [grp][buf], pad 68
  __shared__ __align__(16) f16 at[2][2][64][68];
  __shared__ __align__(16) float cts[2][2][64];
  __shared__ __align__(16) float cmb[256][67];     // combine buffer

  f32x4 racc[2][4];
  #pragma unroll
  for (int sub=0;sub<2;sub++)
    #pragma unroll
    for (int df=0;df<4;df++) racc[sub][df] = (f32x4){0.f,0.f,0.f,0.f};

  // staging: 512 threads/group, 1 chunk each of ks and at per tile
  int local = tid & 511;
  int srow = local>>3, scol = (local&7)*8;
  const f16* kg = k16    + ((size_t)bh*S_ + srow)*64 + scol;
  const f16* ag = alphaT + ((size_t)bh*64 + srow)*S_ + scol;
  const float* ctb = ct + (size_t)bh*S_;
  int lct = local&63;

  f16x8 kv, av; float ctp;
  auto LOADT = [&](int t0){
    kv  = *(const f16x8*)(kg + (size_t)t0*64);
    av  = *(const f16x8*)(ag + t0);
    ctp = ctb[t0 + lct];
  };
  auto STORET = [&](int b){
    *(f16x8*)&ks[grp][b][srow][scol] = kv;
    *(f16x8*)&at[grp][b][srow][scol] = av;
    cts[grp][b][lct] = ctp;
  };

  LOADT(tb);
  STORET(0);
  LOADT(tb+64);
  __syncthreads();

  for (int tt=0; tt<16; tt++){
    int b = tt&1;
    if (tt<15) STORET(b^1);
    if (tt<14) LOADT(tb + (tt+2)*64);
    #pragma unroll
    for (int tf=0; tf<4; tf++){
      f16x8 ka0 = *(const f16x8*)&ks[grp][b][tf*16+lr_][lg*8];
      f16x8 ka1 = *(const f16x8*)&ks[grp][b][tf*16+lr_][32+lg*8];
      f32x4 ctv = *(const f32x4*)&cts[grp][b][tf*16 + lg*4];
      f16x4 paf[2];
      #pragma unroll
      for (int sub=0; sub<2; sub++){
        f32x4 sacc = (f32x4){0.f,0.f,0.f,0.f};
        sacc = __builtin_amdgcn_mfma_f32_16x16x32_f16(ka0, q0[sub], sacc, 0,0,0);
        sacc = __builtin_amdgcn_mfma_f32_16x16x32_f16(ka1, q1[sub], sacc, 0,0,0);
        float p0 = exp2_(fmaf(acoef, sacc[0], bsv[sub] + ctv[0]));
        float p1 = exp2_(fmaf(acoef, sacc[1], bsv[sub] + ctv[1]));
        float p2 = exp2_(fmaf(acoef, sacc[2], bsv[sub] + ctv[2]));
        float p3 = exp2_(fmaf(acoef, sacc[3], bsv[sub] + ctv[3]));
        f16x2 lo = cvt2(p0,p1), hi = cvt2(p2,p3);
        paf[sub][0]=lo[0]; paf[sub][1]=lo[1]; paf[sub][2]=hi[0]; paf[sub][3]=hi[1];
      }
      #pragma unroll
      for (int df=0; df<4; df++){
        f16x4 bfr = *(const f16x4*)&at[grp][b][df*16+lr_][tf*16+lg*4];
        #pragma unroll
        for (int sub=0; sub<2; sub++)
          racc[sub][df] = __builtin_amdgcn_mfma_f32_16x16x16f16(paf[sub], bfr, racc[sub][df], 0,0,0);
      }
    }
    __syncthreads();
  }

  // ---- epilogue ----
  // grp 1 -> cmb; all threads stage lr rows into lrs (overlay on dead ks)
  float* lrs = (float*)ks;                   // [256][17] padded
  float* ws  = (float*)at;                   // [8][16][64] wave partials
  int h = bh&15;
  if (grp==1){
    #pragma unroll
    for (int sub=0; sub<2; sub++)
      #pragma unroll
      for (int df=0; df<4; df++)
        #pragma unroll
        for (int rg=0; rg<4; rg++)
          cmb[gw*32 + sub*16 + lg*4 + rg][df*16 + lr_] = racc[sub][df][rg];
  }
  if (mode==0){
    #pragma unroll
    for (int c=0;c<4;c++){
      int flat = tid*4 + c;                  // 4096 = 256 rows x 16 r
      int sl = flat>>4, r = flat&15;
      lrs[sl*17 + r] = lr32[((size_t)h*S_ + s0 + sl)*16 + r];
    }
  }
  __syncthreads();

  if (grp==0){
    if (mode==0){
      float lam = softplus_(lmp[0]) + 1e-6f;
      // resid into racc (in-place), write global
      #pragma unroll
      for (int sub=0; sub<2; sub++)
        #pragma unroll
        for (int df=0; df<4; df++)
          #pragma unroll
          for (int rg=0; rg<4; rg++){
            int sl = gw*32 + sub*16 + lg*4 + rg;
            int dd = df*16 + lr_;
            size_t gi = ((size_t)bh*S_ + s0 + sl)*64 + dd;
            float rv = v32[gi] - (racc[sub][df][rg] + cmb[sl][dd]) - lam*alpha32[gi];
            racc[sub][df][rg] = rv;
            resid[gi] = rv;
          }
      // fused lr^T @ resid partial: r outer, 4 accumulators
      #pragma unroll
      for (int r=0; r<16; r++){
        float p[4] = {0.f,0.f,0.f,0.f};
        #pragma unroll
        for (int sub=0; sub<2; sub++)
          #pragma unroll
          for (int rg=0; rg<4; rg++){
            int sl = gw*32 + sub*16 + lg*4 + rg;
            float lv = lrs[sl*17 + r];
            #pragma unroll
            for (int df=0; df<4; df++)
              p[df] = fmaf(lv, racc[sub][df][rg], p[df]);
          }
        #pragma unroll
        for (int df=0; df<4; df++){
          float v = p[df];
          v += __shfl_xor(v, 16);
          v += __shfl_xor(v, 32);
          if (lane < 16) ws[(gw*16 + r)*64 + df*16 + lane] = v;
        }
      }
    } else {
      int b2 = bh>>4;
      #pragma unroll
      for (int sub=0; sub<2; sub++)
        #pragma unroll
        for (int df=0; df<4; df++)
          #pragma unroll
          for (int rg=0; rg<4; rg++){
            int sl = gw*32 + sub*16 + lg*4 + rg;
            int dd = df*16 + lr_;
            float rv = racc[sub][df][rg] + cmb[sl][dd];
            y16[((size_t)(b2*S_+s0+sl))*1024 + h*64 + dd] = (f16)rv;
          }
    }
  }
  if (mode==0){
    __syncthreads();
    // reduce 8 wave-partials -> rbuf[chunk = s-block]
    int r = tid>>6, dd = tid&63;             // 1024 outputs
    float acc = 0.f;
    #pragma unroll
    for (int g2=0; g2<8; g2++) acc += ws[(g2*16 + r)*64 + dd];
    int chunk = id>>5;
    rbuf[((size_t)(chunk*32+bh)*16 + r)*64 + dd] = acc;
  }
}

// rbuf[sc,bh,r,d] = sum_{s in chunk sc} lr[h,s,r]*rsd[bh,s,d]  (8 chunks of 256)
// used only for iteration 1 (resid = v)
__global__ __launch_bounds__(256) void reduce_t_k(
    const float* __restrict__ lr32, const float* __restrict__ rsd, float* __restrict__ rbuf)
{
  int dblk = blockIdx.x, bh = blockIdx.y, sc = blockIdx.z, h = bh&15;
  int tid = threadIdx.x, r = tid>>4, dc = tid&15;
  __shared__ __align__(16) float lr_s[128][20];
  __shared__ __align__(16) float rs[128][20];
  float acc = 0.f;
  int row = tid>>1, c8 = (tid&1)*8;
  for (int s0=sc*256; s0<sc*256+256; s0+=128){
    const float* lp = lr32 + ((size_t)h*S_ + s0 + row)*16 + c8;
    const float* rp = rsd  + ((size_t)bh*S_ + s0 + row)*64 + dblk*16 + c8;
    float4 l0 = *(const float4*)lp, l1 = *(const float4*)(lp+4);
    float4 r0 = *(const float4*)rp, r1 = *(const float4*)(rp+4);
    *(float4*)&lr_s[row][c8]   = l0; *(float4*)&lr_s[row][c8+4] = l1;
    *(float4*)&rs[row][c8]     = r0; *(float4*)&rs[row][c8+4]   = r1;
    __syncthreads();
    #pragma unroll 8
    for (int ss=0; ss<128; ss++) acc += lr_s[ss][r]*rs[ss][dc];
    __syncthreads();
  }
  rbuf[((size_t)(sc*32+bh)*16 + r)*64 + dblk*16 + dc] = acc;
}

// alpha = clip(alpha + dp*resid + lr@t), t = sum of 8 rbuf partials
__global__ __launch_bounds__(256) void update_k(
    const float* __restrict__ rsd, const float* __restrict__ alpha_in, int alpha_zero,
    const float* __restrict__ lr32, const float* __restrict__ rbuf,
    const float* __restrict__ dpp,
    float* __restrict__ alpha_out, f16* __restrict__ alphaT)
{
  int sblk = blockIdx.x, bh = blockIdx.y, h = bh&15, s0 = sblk*64;
  int tid = threadIdx.x;
  __shared__ __align__(16) float tb_s[16][64];
  __shared__ __align__(16) float lr_s[64][20];
  __shared__ float dp_s[64];
  __shared__ __align__(16) f16 at_s[64][72];
  {
    float4 t4 = {0.f,0.f,0.f,0.f};
    #pragma unroll
    for (int sc=0; sc<8; sc++){
      float4 p4 = *(const float4*)(rbuf + (size_t)(sc*32+bh)*1024 + tid*4);
      t4.x += p4.x; t4.y += p4.y; t4.z += p4.z; t4.w += p4.w;
    }
    *(float4*)&((float*)tb_s)[tid*4] = t4;
    int row = tid>>2, c4 = (tid&3)*4;
    float4 l4 = *(const float4*)(lr32 + ((size_t)h*S_ + s0 + row)*16 + c4);
    *(float4*)&lr_s[row][c4] = l4;
    if (tid < 64) dp_s[tid] = dpp[(size_t)bh*S_ + s0 + tid];
  }
  __syncthreads();
  #pragma unroll
  for (int i=0;i<16;i++){
    int idx = i*256 + tid;
    int sl = idx>>6, dd = idx&63;
    size_t gi = ((size_t)bh*S_ + s0 + sl)*64 + dd;
    float rv = rsd[gi];
    float av = alpha_zero ? 0.f : alpha_in[gi];
    float acc = av + dp_s[sl]*rv;
    #pragma unroll
    for (int rr=0; rr<16; rr++) acc += lr_s[sl][rr]*tb_s[rr][dd];
    acc = fminf(fmaxf(acc, -10.f), 10.f);
    alpha_out[gi] = acc;
    at_s[dd][sl] = (f16)acc;
  }
  __syncthreads();
  int dd = tid>>2, c16 = (tid&3)*16;
  f16* dst = alphaT + ((size_t)bh*64 + dd)*S_ + s0 + c16;
  *(f16x8*)dst     = *(const f16x8*)&at_s[dd][c16];
  *(f16x8*)(dst+8) = *(const f16x8*)&at_s[dd][c16+8];
}

// ---------------------------------------------------------------------------
extern "C" void kernel_launch(void* const* d_in, const int* in_sizes, int n_in,
                              void* d_out, int out_size, void* d_ws, size_t ws_size,
                              hipStream_t stream)
{
  const float* x   = (const float*)d_in[0];
  const float* wq  = (const float*)d_in[1];
  const float* wk  = (const float*)d_in[2];
  const float* wv  = (const float*)d_in[3];
  const float* wo  = (const float*)d_in[4];
  const float* bwp = (const float*)d_in[5];
  const float* dsp = (const float*)d_in[6];
  const float* rgp = (const float*)d_in[7];
  const float* pos = (const float*)d_in[8];
  const float* hpj = (const float*)d_in[9];
  const float* lmp = (const float*)d_in[10];
  float* outp = (float*)d_out;

  char* base = (char*)d_ws;
  size_t off = 0;
  auto carve = [&](size_t bytes)->char* {
    char* p = base + off; off += (bytes + 255) & ~(size_t)255; return p;
  };
  f16*   x16    = (f16*)  carve((size_t)4096*1024*2);     // 8 MB
  f16*   wqkv16 = (f16*)  carve((size_t)3072*1024*2);     // 6 MB
  f16*   wo16   = (f16*)  carve((size_t)1024*1024*2);     // 2 MB
  f16*   q16    = (f16*)  carve((size_t)BH_*S_*64*2);     // 8 MB
  f16*   k16    = (f16*)  carve((size_t)BH_*S_*64*2);     // 8 MB
  float* v32    = (float*)carve((size_t)BH_*S_*64*4);     // 16 MB
  float* alpha  = (float*)carve((size_t)BH_*S_*64*4);     // 16 MB
  f16*   alphaT = (f16*)  carve((size_t)BH_*64*S_*2);     // 8 MB
  float* resid  = (float*)carve((size_t)BH_*S_*64*4);     // 16 MB
  f16*   y16    = (f16*)  carve((size_t)4096*1024*2);     // 8 MB
  float* bs     = (float*)carve((size_t)BH_*S_*4);
  float* ct     = (float*)carve((size_t)BH_*S_*4);
  float* dp     = (float*)carve((size_t)BH_*S_*4);
  float* lr32   = (float*)carve((size_t)H_*S_*16*4);      // 2 MB
  float* rbuf   = (float*)carve((size_t)8*BH_*16*64*4);   // 2 MB

  // f32 -> f16 conversions
  cvt_k<<<2048,256,0,stream>>>(x,  x16,               4096*1024/8);
  cvt_k<<< 512,256,0,stream>>>(wq, wqkv16,            1024*1024/8);
  cvt_k<<< 512,256,0,stream>>>(wk, wqkv16+1024*1024,  1024*1024/8);
  cvt_k<<< 512,256,0,stream>>>(wv, wqkv16+2*1024*1024,1024*1024/8);
  cvt_k<<< 512,256,0,stream>>>(wo, wo16,              1024*1024/8);
  // fused QKV projection
  gemm16_k<<<768,256,0,stream>>>(x16, wqkv16, q16, k16, v32, nullptr, 0);
  stats_k<<<256,256,0,stream>>>(q16,k16,bwp,dsp,rgp,bs,ct,dp);
  lr_k<<<2048,256,0,stream>>>(pos,hpj,lr32);
  // iteration 1: alpha=0 -> residual = v
  reduce_t_k<<<dim3(4,32,8),256,0,stream>>>(lr32, v32, rbuf);
  update_k<<<dim3(32,32),256,0,stream>>>(v32, alpha, 1, lr32, rbuf, dp, alpha, alphaT);
  // iterations 2..8 (apply fuses resid + lr^T@resid partials)
  for (int it=1; it<8; ++it){
    apply_k<<<256,1024,0,stream>>>(q16,k16,alphaT,bs,ct,v32,alpha,bwp,lmp,lr32,rbuf,resid,nullptr,0);
    update_k<<<dim3(32,32),256,0,stream>>>(resid, alpha, 0, lr32, rbuf, dp, alpha, alphaT);
  }
  // final: out = K @ alpha, then output projection
  apply_k<<<256,1024,0,stream>>>(q16,k16,alphaT,bs,ct,v32,alpha,bwp,lmp,lr32,rbuf,resid,y16,1);
  gemm16_k<<<256,256,0,stream>>>(y16, wo16, nullptr, nullptr, nullptr, outp, 1);
}